// Round 1
// baseline (1999.568 us; speedup 1.0000x reference)
//
#include <hip/hip_runtime.h>
#include <math.h>

namespace {
constexpr int kB = 4, kL = 2048, kDM = 1024;
constexpr int kH = 16, kG = 4, kP = 64, kN = 64, kR = 2;
constexpr int kDPROJ = 3084;
constexpr int COL_Z = 0, COL_XP = 1024, COL_B = 2048, COL_C = 2560, COL_DT = 3072, COL_A = 3076;
constexpr int kTOK = kB * kL;          // 8192
constexpr int kCH = 64, kNC = kL / kCH; // chunk=64, 32 chunks
}

// ---------------- K1: in_proj GEMM (f32): proj[i,j] = sum_k u[i,k]*W[j,k] + b[j]
__global__ __launch_bounds__(256) void k_inproj(const float* __restrict__ U,
                                                const float* __restrict__ W,
                                                const float* __restrict__ bias,
                                                float* __restrict__ proj) {
  __shared__ float As[16][65];
  __shared__ float Bs[16][65];
  int row0 = blockIdx.x * 64;
  int col0 = blockIdx.y * 64;
  int tid = threadIdx.x;
  int tx = tid & 15, ty = tid >> 4;
  float acc[4][4];
#pragma unroll
  for (int i = 0; i < 4; ++i)
#pragma unroll
    for (int j = 0; j < 4; ++j) acc[i][j] = 0.f;

  int r = tid >> 2, kq = (tid & 3) * 4;
  for (int k0 = 0; k0 < kDM; k0 += 16) {
    float4 a = *reinterpret_cast<const float4*>(&U[(size_t)(row0 + r) * kDM + k0 + kq]);
    As[kq + 0][r] = a.x; As[kq + 1][r] = a.y; As[kq + 2][r] = a.z; As[kq + 3][r] = a.w;
    int jcol = col0 + r;
    float4 b = make_float4(0.f, 0.f, 0.f, 0.f);
    if (jcol < kDPROJ) b = *reinterpret_cast<const float4*>(&W[(size_t)jcol * kDM + k0 + kq]);
    Bs[kq + 0][r] = b.x; Bs[kq + 1][r] = b.y; Bs[kq + 2][r] = b.z; Bs[kq + 3][r] = b.w;
    __syncthreads();
#pragma unroll
    for (int kk = 0; kk < 16; ++kk) {
      float av[4], bv[4];
#pragma unroll
      for (int q = 0; q < 4; ++q) av[q] = As[kk][ty * 4 + q];
#pragma unroll
      for (int q = 0; q < 4; ++q) bv[q] = Bs[kk][tx * 4 + q];
#pragma unroll
      for (int i = 0; i < 4; ++i)
#pragma unroll
        for (int j = 0; j < 4; ++j) acc[i][j] += av[i] * bv[j];
    }
    __syncthreads();
  }
#pragma unroll
  for (int i = 0; i < 4; ++i) {
    int rr = row0 + ty * 4 + i;
#pragma unroll
    for (int j = 0; j < 4; ++j) {
      int cc = col0 + tx * 4 + j;
      if (cc < kDPROJ) proj[(size_t)rr * kDPROJ + cc] = acc[i][j] + bias[cc];
    }
  }
}

// ---------------- K2: dt prep + f64 scans: dtg, cumalog (f32), cumdt (f64)
__global__ __launch_bounds__(256) void k_dtprep(const float* __restrict__ proj,
                                                float* __restrict__ dtg,
                                                float* __restrict__ cumalog,
                                                double* __restrict__ cumdt) {
  int bg = blockIdx.x;
  int b = bg / kG, g = bg % kG;
  int tid = threadIdx.x;
  __shared__ double s_dt[256], s_al[256];
  double loc_dt[8], loc_al[8];
  double sdt = 0.0, sal = 0.0;
#pragma unroll
  for (int q = 0; q < 8; ++q) {
    int t = tid * 8 + q;
    size_t i = (size_t)(b * kL + t) * kDPROJ;
    float rd = proj[i + COL_DT + g];
    float ra = proj[i + COL_A + g];
    float dt = rd > 20.f ? rd : log1pf(expf(rd));
    float al = -expf(ra) * dt;
    dtg[(size_t)(b * kL + t) * kG + g] = dt;
    sdt += (double)dt; loc_dt[q] = sdt;
    sal += (double)al; loc_al[q] = sal;
  }
  s_dt[tid] = sdt; s_al[tid] = sal;
  __syncthreads();
  for (int off = 1; off < 256; off <<= 1) {
    double a = 0.0, c = 0.0;
    if (tid >= off) { a = s_dt[tid - off]; c = s_al[tid - off]; }
    __syncthreads();
    s_dt[tid] += a; s_al[tid] += c;
    __syncthreads();
  }
  double base_dt = tid ? s_dt[tid - 1] : 0.0;
  double base_al = tid ? s_al[tid - 1] : 0.0;
#pragma unroll
  for (int q = 0; q < 8; ++q) {
    int t = tid * 8 + q;
    size_t idx = (size_t)(b * kL + t) * kG + g;
    cumdt[idx] = base_dt + loc_dt[q];
    cumalog[idx] = (float)(base_al + loc_al[q]);
  }
}

// ---------------- K3: RMS + bias + RoPE rotate of B/C, in place in proj
__global__ __launch_bounds__(256) void k_rotate(float* __restrict__ proj,
                                                const double* __restrict__ cumdt,
                                                const float* __restrict__ theta_log,
                                                const float* __restrict__ normB_w,
                                                const float* __restrict__ normC_w,
                                                const float* __restrict__ bias_B,
                                                const float* __restrict__ bias_C) {
  int tok = blockIdx.x;
  int tid = threadIdx.x;
  __shared__ float buf[256];
  __shared__ float red[4];
  size_t rowoff = (size_t)tok * kDPROJ;
  int half = tid >> 7;      // 0 = B, 1 = C
  int j = tid & 127;        // j = n*2 + r
  int wave = tid >> 6;
  for (int g = 0; g < kG; ++g) {
    int col = (half ? COL_C : COL_B) + g * 128 + j;
    float v = proj[rowoff + col];
    float ss = v * v;
    for (int o = 1; o < 64; o <<= 1) ss += __shfl_xor(ss, o);
    if ((tid & 63) == 0) red[wave] = ss;
    __syncthreads();
    float tot = red[half * 2] + red[half * 2 + 1];
    float scale = rsqrtf(tot / 128.f + 1e-5f);
    const float* nw = half ? normC_w : normB_w;
    const float* bb = half ? bias_C : bias_B;
    float nv = v * scale * nw[j] + bb[g * 128 + j];
    buf[tid] = nv;
    __syncthreads();
    float other = buf[tid ^ 2];
    int n = j >> 1, k = n >> 1;
    bool isRe = (n & 1) == 0;
    double theta = exp((double)theta_log[g * 32 + k]);
    double ang = theta * cumdt[(size_t)tok * kG + g];
    const double twopi = 6.283185307179586476925286766559;
    double rem = ang - floor(ang / twopi) * twopi;
    float cc = cosf((float)rem), sn = sinf((float)rem);
    float out = isRe ? (nv * cc - other * sn) : (other * sn + nv * cc);
    proj[rowoff + col] = out;
    __syncthreads();
  }
}

// ---------------- K4: xup Kron-MoE -> xmoe (B,L,H,128)
__global__ __launch_bounds__(256) void k_xup(const float* __restrict__ proj,
                                             const float* __restrict__ router,
                                             const float* __restrict__ Ae,
                                             const float* __restrict__ Be,
                                             const float* __restrict__ scale_,
                                             const float* __restrict__ bias_,
                                             float* __restrict__ xmoe) {
  int wave = threadIdx.x >> 6, lane = threadIdx.x & 63;
  int unit = blockIdx.x * 4 + wave;
  int tok = unit >> 4, h = unit & 15;
  __shared__ float xs_all[4][64];
  __shared__ float Rs[64][65];
  for (int m = threadIdx.x; m < 64 * 64; m += 256) Rs[m >> 6][m & 63] = router[m];
  float xv = proj[(size_t)tok * kDPROJ + COL_XP + h * 64 + lane];
  xs_all[wave][lane] = xv;
  __syncthreads();
  const float* xs = xs_all[wave];
  double accd = 0.0;
#pragma unroll
  for (int d = 0; d < 64; ++d) accd += (double)Rs[lane][d] * (double)xs[d];
  float logit = (float)accd;
  float v1 = logit; int i1 = lane;
  for (int o = 1; o < 64; o <<= 1) {
    float vv = __shfl_xor(v1, o); int ii = __shfl_xor(i1, o);
    if (vv > v1 || (vv == v1 && ii < i1)) { v1 = vv; i1 = ii; }
  }
  float lm = (lane == i1) ? -INFINITY : logit;
  float v2 = lm; int i2 = lane;
  for (int o = 1; o < 64; o <<= 1) {
    float vv = __shfl_xor(v2, o); int ii = __shfl_xor(i2, o);
    if (vv > v2 || (vv == v2 && ii < i2)) { v2 = vv; i2 = ii; }
  }
  float e12 = expf(v2 - v1);
  float p1 = 1.f / (1.f + e12), p2 = e12 / (1.f + e12);
  float out0 = 0.f, out1 = 0.f;
#pragma unroll
  for (int kk = 0; kk < 2; ++kk) {
    int e = kk ? i2 : i1;
    float pw = kk ? p2 : p1;
    const float* A = Ae + (size_t)e * 64;    // 8x8
    const float* Bm = Be + (size_t)e * 128;  // 16x8
#pragma unroll
    for (int hlf = 0; hlf < 2; ++hlf) {
      int c = lane + hlf * 64;
      int o = c >> 4, p = c & 15;
      float y = 0.f;
#pragma unroll
      for (int i = 0; i < 8; ++i) {
        float t = 0.f;
#pragma unroll
        for (int jj = 0; jj < 8; ++jj) t += xs[i * 8 + jj] * Bm[p * 8 + jj];
        y += A[o * 8 + i] * t;
      }
      if (hlf) out1 += pw * y; else out0 += pw * y;
    }
  }
  float sc = scale_[0];
  size_t ob = (size_t)unit * 128;
  xmoe[ob + lane] = out0 * sc + bias_[lane];
  xmoe[ob + lane + 64] = out1 * sc + bias_[lane + 64];
}

// ---------------- K5: pass A — per-chunk local end state S_c
__global__ __launch_bounds__(256) void k_passA(const float* __restrict__ proj,
                                               const float* __restrict__ xmoe,
                                               const float* __restrict__ dtg,
                                               const float* __restrict__ cumalog,
                                               float* __restrict__ hstate) {
  int bid = blockIdx.x;
  int c = bid & 31, h = (bid >> 5) & 15, b = bid >> 9, g = h >> 2;
  int tid = threadIdx.x;
  __shared__ float Bs[128][65];
  __shared__ float Xs[128][65];
  __shared__ float wv[64];
  int base = c * 64;
  size_t tok0 = (size_t)b * kL + base;
  if (tid < 64) {
    float ca_last = cumalog[(tok0 + 63) * kG + g];
    float ca_s = cumalog[(tok0 + tid) * kG + g];
    float dt = dtg[(tok0 + tid) * kG + g];
    wv[tid] = expf(ca_last - ca_s) * dt;
  }
  __syncthreads();
  for (int m = tid; m < 8192; m += 256) {
    int s = m >> 7, j = m & 127;
    float bval = proj[(tok0 + s) * kDPROJ + COL_B + g * 128 + j];
    Bs[s * 2 + (j & 1)][j >> 1] = bval * wv[s];
    float xval = xmoe[((tok0 + s) * kH + h) * (size_t)128 + j];
    Xs[s * 2 + (j & 1)][j >> 1] = xval;
  }
  __syncthreads();
  int tx = tid & 15, ty = tid >> 4;
  float acc[4][4];
#pragma unroll
  for (int i = 0; i < 4; ++i)
#pragma unroll
    for (int j = 0; j < 4; ++j) acc[i][j] = 0.f;
  for (int k = 0; k < 128; ++k) {
    float a[4], bv[4];
#pragma unroll
    for (int q = 0; q < 4; ++q) a[q] = Bs[k][ty * 4 + q];
#pragma unroll
    for (int q = 0; q < 4; ++q) bv[q] = Xs[k][tx * 4 + q];
#pragma unroll
    for (int i = 0; i < 4; ++i)
#pragma unroll
      for (int j = 0; j < 4; ++j) acc[i][j] += a[i] * bv[j];
  }
  float* out = hstate + (size_t)bid * 4096;
#pragma unroll
  for (int i = 0; i < 4; ++i)
#pragma unroll
    for (int j = 0; j < 4; ++j)
      out[(ty * 4 + i) * 64 + tx * 4 + j] = acc[i][j];
}

// ---------------- K6: pass B — sequential inter-chunk combine (in place: local -> h0)
__global__ __launch_bounds__(256) void k_passB(float* __restrict__ hstate,
                                               const float* __restrict__ cumalog) {
  int bh = blockIdx.x;
  int b = bh >> 4, h = bh & 15, g = h >> 2;
  int tid = threadIdx.x;
  float hrun[16];
#pragma unroll
  for (int q = 0; q < 16; ++q) hrun[q] = 0.f;
  float* Hbase = hstate + (size_t)bh * 32 * 4096;
  for (int c = 0; c < 32; ++c) {
    float ca_last = cumalog[((size_t)b * kL + c * 64 + 63) * kG + g];
    float ca_prev = c ? cumalog[((size_t)b * kL + c * 64 - 1) * kG + g] : 0.f;
    float Dc = expf(ca_last - ca_prev);
    float* Hc = Hbase + (size_t)c * 4096;
#pragma unroll
    for (int q = 0; q < 16; ++q) {
      int idx = tid + q * 256;
      float local = Hc[idx];
      Hc[idx] = hrun[q];
      hrun[q] = Dc * hrun[q] + local;
    }
  }
}

// ---------------- K7: pass C — chunk outputs + fused ydown -> d_out (y1)
__global__ __launch_bounds__(256) void k_passC(const float* __restrict__ proj,
                                               const float* __restrict__ xmoe,
                                               const float* __restrict__ dtg,
                                               const float* __restrict__ cumalog,
                                               const float* __restrict__ hstate,
                                               const float* __restrict__ ydown,
                                               float* __restrict__ outY) {
  int bid = blockIdx.x;
  int c = bid & 31, h = (bid >> 5) & 15, b = bid >> 9, g = h >> 2;
  int tid = threadIdx.x;
  __shared__ float Cs[128][65];
  __shared__ float Bs[128][65];
  __shared__ float Gs[128][129];
  __shared__ float ell[64], dts[64], elx[64];
  int base = c * 64;
  size_t tok0 = (size_t)b * kL + base;
  if (tid < 64) {
    float ca_prev = base ? cumalog[(tok0 - 1) * kG + g] : 0.f;
    float ca_t = cumalog[(tok0 + tid) * kG + g];
    ell[tid] = ca_t - ca_prev;
    elx[tid] = expf(ca_t - ca_prev);
    dts[tid] = dtg[(tok0 + tid) * kG + g];
  }
  for (int m = tid; m < 8192; m += 256) {
    int s = m >> 7, j = m & 127;
    Cs[s * 2 + (j & 1)][j >> 1] = proj[(tok0 + s) * kDPROJ + COL_C + g * 128 + j];
    Bs[s * 2 + (j & 1)][j >> 1] = proj[(tok0 + s) * kDPROJ + COL_B + g * 128 + j];
  }
  __syncthreads();
  { // scores G[(t,r)][(s,r')] with causal decay * dt
    int tx = tid & 15, ty = tid >> 4;
    float acc[8][8];
#pragma unroll
    for (int i = 0; i < 8; ++i)
#pragma unroll
      for (int j = 0; j < 8; ++j) acc[i][j] = 0.f;
    for (int n = 0; n < 64; ++n) {
      float a[8], bv[8];
#pragma unroll
      for (int q = 0; q < 8; ++q) a[q] = Cs[ty * 8 + q][n];
#pragma unroll
      for (int q = 0; q < 8; ++q) bv[q] = Bs[tx * 8 + q][n];
#pragma unroll
      for (int i = 0; i < 8; ++i)
#pragma unroll
        for (int j = 0; j < 8; ++j) acc[i][j] += a[i] * bv[j];
    }
#pragma unroll
    for (int i = 0; i < 8; ++i) {
      int row = ty * 8 + i, t = row >> 1;
#pragma unroll
      for (int j = 0; j < 8; ++j) {
        int col = tx * 8 + j, s = col >> 1;
        float w = (s <= t) ? dts[s] * expf(ell[t] - ell[s]) : 0.f;
        Gs[row][col] = acc[i][j] * w;
      }
    }
  }
  __syncthreads();
  // h0 -> Bs[0..63][0..63]
  for (int m = tid; m < 4096; m += 256)
    Bs[m >> 6][m & 63] = hstate[(size_t)bid * 4096 + m];
  __syncthreads();
  int tx8 = tid & 7, ty32 = tid >> 3;
  float yac[4][8];
#pragma unroll
  for (int i = 0; i < 4; ++i)
#pragma unroll
    for (int j = 0; j < 8; ++j) yac[i][j] = 0.f;
  for (int n = 0; n < 64; ++n) { // y0 = C^T h0
    float a[4], bv[8];
#pragma unroll
    for (int q = 0; q < 4; ++q) a[q] = Cs[ty32 * 4 + q][n];
#pragma unroll
    for (int q = 0; q < 8; ++q) bv[q] = Bs[n][tx8 * 8 + q];
#pragma unroll
    for (int i = 0; i < 4; ++i)
#pragma unroll
      for (int j = 0; j < 8; ++j) yac[i][j] += a[i] * bv[j];
  }
#pragma unroll
  for (int i = 0; i < 4; ++i) {
    float e = elx[(ty32 * 4 + i) >> 1];
#pragma unroll
    for (int j = 0; j < 8; ++j) yac[i][j] *= e;
  }
  __syncthreads();
  // X -> Cs
  for (int m = tid; m < 8192; m += 256) {
    int s = m >> 7, j = m & 127;
    Cs[s * 2 + (j & 1)][j >> 1] = xmoe[((tok0 + s) * kH + h) * (size_t)128 + j];
  }
  __syncthreads();
  for (int k = 0; k < 128; ++k) { // yac += Gs @ X
    float a[4], bv[8];
#pragma unroll
    for (int q = 0; q < 4; ++q) a[q] = Gs[ty32 * 4 + q][k];
#pragma unroll
    for (int q = 0; q < 8; ++q) bv[q] = Cs[k][tx8 * 8 + q];
#pragma unroll
    for (int i = 0; i < 4; ++i)
#pragma unroll
      for (int j = 0; j < 8; ++j) yac[i][j] += a[i] * bv[j];
  }
  __syncthreads();
  // Ys[t][p*2+r] -> Gs rows 0..63 ; Wd[cc][o] -> Bs
#pragma unroll
  for (int i = 0; i < 4; ++i) {
    int row = ty32 * 4 + i, t = row >> 1, r = row & 1;
#pragma unroll
    for (int j = 0; j < 8; ++j) {
      int p = tx8 * 8 + j;
      Gs[t][p * 2 + r] = yac[i][j];
    }
  }
  for (int m = tid; m < 8192; m += 256) {
    int o = m >> 7, cc = m & 127;
    Bs[cc][o] = ydown[m];
  }
  __syncthreads();
  {
    int tx = tid & 15, ty = tid >> 4;
    float oc[4][4];
#pragma unroll
    for (int i = 0; i < 4; ++i)
#pragma unroll
      for (int j = 0; j < 4; ++j) oc[i][j] = 0.f;
    for (int cc = 0; cc < 128; ++cc) {
      float a[4], bv[4];
#pragma unroll
      for (int q = 0; q < 4; ++q) a[q] = Gs[ty * 4 + q][cc];
#pragma unroll
      for (int q = 0; q < 4; ++q) bv[q] = Bs[cc][tx * 4 + q];
#pragma unroll
      for (int i = 0; i < 4; ++i)
#pragma unroll
        for (int j = 0; j < 4; ++j) oc[i][j] += a[i] * bv[j];
    }
#pragma unroll
    for (int i = 0; i < 4; ++i) {
      int t = ty * 4 + i;
#pragma unroll
      for (int j = 0; j < 4; ++j) {
        int o = tx * 4 + j;
        outY[(tok0 + t) * (size_t)1024 + h * 64 + o] = oc[i][j];
      }
    }
  }
}

// ---------------- K8: gate — y = rms(y + x_p * rep(D), pregate_w) * sigmoid(z), in place on d_out
__global__ __launch_bounds__(256) void k_gate(float* __restrict__ y,
                                              const float* __restrict__ proj,
                                              const float* __restrict__ Dv,
                                              const float* __restrict__ pregate_w) {
  int tok = blockIdx.x;
  int tid = threadIdx.x;
  size_t yoff = (size_t)tok * 1024;
  size_t poff = (size_t)tok * kDPROJ;
  __shared__ float red[4];
  float vals[4];
  float ss = 0.f;
#pragma unroll
  for (int q = 0; q < 4; ++q) {
    int j = tid + q * 256;
    float v = y[yoff + j] + proj[poff + COL_XP + j] * Dv[j >> 6];
    vals[q] = v;
    ss += v * v;
  }
  for (int o = 1; o < 64; o <<= 1) ss += __shfl_xor(ss, o);
  if ((tid & 63) == 0) red[tid >> 6] = ss;
  __syncthreads();
  float tot = red[0] + red[1] + red[2] + red[3];
  float scale = rsqrtf(tot / 1024.f + 1e-5f);
#pragma unroll
  for (int q = 0; q < 4; ++q) {
    int j = tid + q * 256;
    float z = proj[poff + COL_Z + j];
    float sig = 1.f / (1.f + expf(-z));
    y[yoff + j] = vals[q] * scale * pregate_w[j] * sig;
  }
}

// ---------------- K9: oup Kron-MoE, in place on d_out
__global__ __launch_bounds__(256) void k_oup(float* __restrict__ y,
                                             const float* __restrict__ router,
                                             const float* __restrict__ Ae,
                                             const float* __restrict__ Be,
                                             const float* __restrict__ scale_,
                                             const float* __restrict__ bias_) {
  int tok = blockIdx.x;
  int tid = threadIdx.x;
  __shared__ float xs[1024];
  __shared__ float Ts[32][33];
  __shared__ float logits_s[64];
  __shared__ double partial[256];
  size_t yoff = (size_t)tok * 1024;
  for (int m = tid; m < 1024; m += 256) xs[m] = y[yoff + m];
  __syncthreads();
  {
    int e = tid & 63, q = tid >> 6;
    double acc = 0.0;
    const float* rw = router + (size_t)e * 1024 + q * 256;
    const float* xv = xs + q * 256;
    for (int d = 0; d < 256; ++d) acc += (double)rw[d] * (double)xv[d];
    partial[tid] = acc;
  }
  __syncthreads();
  if (tid < 64) {
    double l = partial[tid] + partial[tid + 64] + partial[tid + 128] + partial[tid + 192];
    logits_s[tid] = (float)l;
  }
  __syncthreads();
  float v1 = -INFINITY; int i1 = -1;
  for (int e = 0; e < 64; ++e) { float v = logits_s[e]; if (v > v1) { v1 = v; i1 = e; } }
  float v2 = -INFINITY; int i2 = -1;
  for (int e = 0; e < 64; ++e) { if (e == i1) continue; float v = logits_s[e]; if (v > v2) { v2 = v; i2 = e; } }
  float e12 = expf(v2 - v1);
  float p1 = 1.f / (1.f + e12), p2 = e12 / (1.f + e12);
  float out[4] = {0.f, 0.f, 0.f, 0.f};
  for (int kk = 0; kk < 2; ++kk) {
    int e = kk ? i2 : i1;
    float pw = kk ? p2 : p1;
    const float* A = Ae + (size_t)e * 1024;
    const float* Bm = Be + (size_t)e * 1024;
    __syncthreads();
    for (int m = tid; m < 1024; m += 256) {
      int i = m >> 5, p = m & 31;
      float t = 0.f;
#pragma unroll
      for (int j = 0; j < 32; ++j) t += xs[i * 32 + j] * Bm[p * 32 + j];
      Ts[i][p] = t;
    }
    __syncthreads();
#pragma unroll
    for (int q = 0; q < 4; ++q) {
      int cc = tid + q * 256;
      int o = cc >> 5, p = cc & 31;
      float a2 = 0.f;
#pragma unroll
      for (int i = 0; i < 32; ++i) a2 += A[o * 32 + i] * Ts[i][p];
      out[q] += pw * a2;
    }
  }
  float sc = scale_[0];
#pragma unroll
  for (int q = 0; q < 4; ++q) {
    int cc = tid + q * 256;
    y[yoff + cc] = out[q] * sc + bias_[cc];
  }
}

extern "C" void kernel_launch(void* const* d_in, const int* in_sizes, int n_in,
                              void* d_out, int out_size, void* d_ws, size_t ws_size,
                              hipStream_t stream) {
  const float* u          = (const float*)d_in[0];
  const float* in_proj_w  = (const float*)d_in[1];
  const float* in_proj_b  = (const float*)d_in[2];
  const float* xup_router = (const float*)d_in[3];
  const float* xup_A      = (const float*)d_in[4];
  const float* xup_B      = (const float*)d_in[5];
  const float* xup_scale  = (const float*)d_in[6];
  const float* xup_bias   = (const float*)d_in[7];
  const float* ydown_w    = (const float*)d_in[8];
  const float* oup_router = (const float*)d_in[9];
  const float* oup_A      = (const float*)d_in[10];
  const float* oup_B      = (const float*)d_in[11];
  const float* oup_scale  = (const float*)d_in[12];
  const float* oup_bias   = (const float*)d_in[13];
  const float* theta_log  = (const float*)d_in[14];
  const float* Dv         = (const float*)d_in[15];
  const float* normB_w    = (const float*)d_in[16];
  const float* normC_w    = (const float*)d_in[17];
  const float* bias_B     = (const float*)d_in[18];
  const float* bias_C     = (const float*)d_in[19];
  const float* pregate_w  = (const float*)d_in[20];

  char* ws = (char*)d_ws;
  float* proj = (float*)ws;      ws += (size_t)kTOK * kDPROJ * 4;   // 101.06 MB
  float* dtg = (float*)ws;       ws += (size_t)kTOK * kG * 4;       // 128 KB
  float* cumalog = (float*)ws;   ws += (size_t)kTOK * kG * 4;       // 128 KB
  double* cumdt = (double*)ws;   ws += (size_t)kTOK * kG * 8;       // 256 KB
  float* xmoe = (float*)ws;      ws += (size_t)kTOK * kH * 128 * 4; // 67.1 MB
  float* hstate = (float*)ws;    ws += (size_t)kB * kH * kNC * 4096 * 4; // 33.55 MB
  float* outY = (float*)d_out;

  k_inproj<<<dim3(kTOK / 64, (kDPROJ + 63) / 64), dim3(256), 0, stream>>>(u, in_proj_w, in_proj_b, proj);
  k_dtprep<<<dim3(kB * kG), dim3(256), 0, stream>>>(proj, dtg, cumalog, cumdt);
  k_rotate<<<dim3(kTOK), dim3(256), 0, stream>>>(proj, cumdt, theta_log, normB_w, normC_w, bias_B, bias_C);
  k_xup<<<dim3(kTOK * kH / 4), dim3(256), 0, stream>>>(proj, xup_router, xup_A, xup_B, xup_scale, xup_bias, xmoe);
  k_passA<<<dim3(kB * kH * kNC), dim3(256), 0, stream>>>(proj, xmoe, dtg, cumalog, hstate);
  k_passB<<<dim3(kB * kH), dim3(256), 0, stream>>>(hstate, cumalog);
  k_passC<<<dim3(kB * kH * kNC), dim3(256), 0, stream>>>(proj, xmoe, dtg, cumalog, hstate, ydown_w, outY);
  k_gate<<<dim3(kTOK), dim3(256), 0, stream>>>(outY, proj, Dv, pregate_w);
  k_oup<<<dim3(kTOK), dim3(256), 0, stream>>>(outY, oup_router, oup_A, oup_B, oup_scale, oup_bias);
}

// Round 2
// 1183.538 us; speedup vs baseline: 1.6895x; 1.6895x over previous
//
#include <hip/hip_runtime.h>
#include <hip/hip_bf16.h>
#include <math.h>

namespace {
constexpr int kB = 4, kL = 2048, kDM = 1024;
constexpr int kH = 16, kG = 4;
constexpr int kDPROJ = 3084;
constexpr int COL_Z = 0, COL_XP = 1024, COL_B = 2048, COL_C = 2560, COL_DT = 3072, COL_A = 3076;
constexpr int kTOK = kB * kL;           // 8192
constexpr int kNC = kL / 64;            // 32 chunks
constexpr int kNPAD = 3200;             // W padded rows (25 * 128)
}

typedef __attribute__((ext_vector_type(8))) __bf16 bf16x8;
typedef __attribute__((ext_vector_type(8))) unsigned short u16x8;
typedef __attribute__((ext_vector_type(4))) float f32x4;

#define GLDS16(gp, lp)                                                          \
  __builtin_amdgcn_global_load_lds(                                             \
      (const __attribute__((address_space(1))) void*)(gp),                      \
      (__attribute__((address_space(3))) void*)(lp), 16, 0, 0)

__device__ __forceinline__ unsigned short bf16_rne(float f) {
  unsigned u = __builtin_bit_cast(unsigned, f);
  unsigned r = u + 0x7fffu + ((u >> 16) & 1u);
  return (unsigned short)(r >> 16);
}

// ---------------- K0a: split U -> (hi, lo) bf16
__global__ __launch_bounds__(256) void k_split_u(const float* __restrict__ X,
                                                 unsigned short* __restrict__ hi,
                                                 unsigned short* __restrict__ lo) {
  int i = blockIdx.x * 256 + threadIdx.x;   // one float4 per thread, n4 = 2097152
  float4 x = ((const float4*)X)[i];
  float xs[4] = {x.x, x.y, x.z, x.w};
  ushort4 hv, lv;
  unsigned short hq[4], lq[4];
#pragma unroll
  for (int q = 0; q < 4; ++q) {
    unsigned short h = bf16_rne(xs[q]);
    float hf = __builtin_bit_cast(float, (unsigned)h << 16);
    hq[q] = h;
    lq[q] = bf16_rne(xs[q] - hf);
  }
  hv.x = hq[0]; hv.y = hq[1]; hv.z = hq[2]; hv.w = hq[3];
  lv.x = lq[0]; lv.y = lq[1]; lv.z = lq[2]; lv.w = lq[3];
  ((ushort4*)hi)[i] = hv;
  ((ushort4*)lo)[i] = lv;
}

// ---------------- K0b: split W -> (hi, lo) bf16, padded to kNPAD rows (zeros)
__global__ __launch_bounds__(256) void k_split_w(const float* __restrict__ X,
                                                 unsigned short* __restrict__ hi,
                                                 unsigned short* __restrict__ lo) {
  int i = blockIdx.x * 256 + threadIdx.x;   // n4 = kNPAD*kDM/4 = 819200
  int row = i >> 8;                          // i*4/1024
  float4 x = make_float4(0.f, 0.f, 0.f, 0.f);
  if (row < kDPROJ) x = ((const float4*)X)[i];
  float xs[4] = {x.x, x.y, x.z, x.w};
  ushort4 hv, lv;
  unsigned short hq[4], lq[4];
#pragma unroll
  for (int q = 0; q < 4; ++q) {
    unsigned short h = bf16_rne(xs[q]);
    float hf = __builtin_bit_cast(float, (unsigned)h << 16);
    hq[q] = h;
    lq[q] = bf16_rne(xs[q] - hf);
  }
  hv.x = hq[0]; hv.y = hq[1]; hv.z = hq[2]; hv.w = hq[3];
  lv.x = lq[0]; lv.y = lq[1]; lv.z = lq[2]; lv.w = lq[3];
  ((ushort4*)hi)[i] = hv;
  ((ushort4*)lo)[i] = lv;
}

// ---------------- K1: in_proj GEMM via split-bf16 MFMA
// proj[i,j] = sum_k U[i,k] W[j,k] + b[j];  U = Uhi+Ulo, W = Whi+Wlo (drop lo*lo)
__global__ __launch_bounds__(256) void k_inproj_mfma(
    const unsigned short* __restrict__ Uhi, const unsigned short* __restrict__ Ulo,
    const unsigned short* __restrict__ Whi, const unsigned short* __restrict__ Wlo,
    const float* __restrict__ bias, float* __restrict__ proj) {
  __shared__ unsigned short lds_u[16384];   // 4 tiles x 128 x 32 bf16 = 32 KB
  const int tid = threadIdx.x;
  const int wave = tid >> 6, lane = tid & 63;
  const int wm = wave >> 1, wn = wave & 1;
  const int row0 = blockIdx.x * 128, col0 = blockIdx.y * 128;
  const int fr = lane & 15, kq = lane >> 4;

  f32x4 acc[4][4];
#pragma unroll
  for (int i = 0; i < 4; ++i)
#pragma unroll
    for (int j = 0; j < 4; ++j) acc[i][j] = (f32x4){0.f, 0.f, 0.f, 0.f};

  const int s0 = wave * 64 + lane;

  for (int k0 = 0; k0 < kDM; k0 += 32) {
#pragma unroll
    for (int q = 0; q < 2; ++q) {
      const int slot = q * 256 + s0;
      const int r = slot >> 2;
      // swizzle: LDS is linear; fetch the element that the swizzled reader expects
      const int ce = ((slot & 3) ^ ((r >> 1) & 3)) * 8;
      const size_t ao = (size_t)(row0 + r) * kDM + k0 + ce;
      const size_t bo = (size_t)(col0 + r) * kDM + k0 + ce;
      const int lb = (q * 256 + wave * 64) * 16;  // wave-uniform lds byte base
      GLDS16(Uhi + ao, (char*)lds_u + lb);
      GLDS16(Ulo + ao, (char*)lds_u + 8192 + lb);
      GLDS16(Whi + bo, (char*)lds_u + 16384 + lb);
      GLDS16(Wlo + bo, (char*)lds_u + 24576 + lb);
    }
    __syncthreads();
    bf16x8 ahi[4], alo[4], bhi[4], blo[4];
#pragma unroll
    for (int mi = 0; mi < 4; ++mi) {
      int r = wm * 64 + mi * 16 + fr;
      int off = r * 32 + ((kq ^ ((r >> 1) & 3)) * 8);
      ahi[mi] = __builtin_bit_cast(bf16x8, *(const u16x8*)(lds_u + off));
      alo[mi] = __builtin_bit_cast(bf16x8, *(const u16x8*)(lds_u + 4096 + off));
    }
#pragma unroll
    for (int ni = 0; ni < 4; ++ni) {
      int r = wn * 64 + ni * 16 + fr;
      int off = r * 32 + ((kq ^ ((r >> 1) & 3)) * 8);
      bhi[ni] = __builtin_bit_cast(bf16x8, *(const u16x8*)(lds_u + 8192 + off));
      blo[ni] = __builtin_bit_cast(bf16x8, *(const u16x8*)(lds_u + 12288 + off));
    }
#pragma unroll
    for (int mi = 0; mi < 4; ++mi)
#pragma unroll
      for (int ni = 0; ni < 4; ++ni) {
        acc[mi][ni] = __builtin_amdgcn_mfma_f32_16x16x32_bf16(ahi[mi], bhi[ni], acc[mi][ni], 0, 0, 0);
        acc[mi][ni] = __builtin_amdgcn_mfma_f32_16x16x32_bf16(ahi[mi], blo[ni], acc[mi][ni], 0, 0, 0);
        acc[mi][ni] = __builtin_amdgcn_mfma_f32_16x16x32_bf16(alo[mi], bhi[ni], acc[mi][ni], 0, 0, 0);
      }
    __syncthreads();
  }

  const int orow = row0 + wm * 64, ocol = col0 + wn * 64;
#pragma unroll
  for (int mi = 0; mi < 4; ++mi)
#pragma unroll
    for (int ni = 0; ni < 4; ++ni) {
      int cg = ocol + ni * 16 + fr;
      if (cg < kDPROJ) {
        float bv = bias[cg];
#pragma unroll
        for (int r = 0; r < 4; ++r) {
          int rg = orow + mi * 16 + kq * 4 + r;
          proj[(size_t)rg * kDPROJ + cg] = acc[mi][ni][r] + bv;
        }
      }
    }
}

// ---------------- K2: dt prep + f64 scans
__global__ __launch_bounds__(256) void k_dtprep(const float* __restrict__ proj,
                                                float* __restrict__ dtg,
                                                float* __restrict__ cumalog,
                                                double* __restrict__ cumdt) {
  int bg = blockIdx.x;
  int b = bg / kG, g = bg % kG;
  int tid = threadIdx.x;
  __shared__ double s_dt[256], s_al[256];
  double loc_dt[8], loc_al[8];
  double sdt = 0.0, sal = 0.0;
#pragma unroll
  for (int q = 0; q < 8; ++q) {
    int t = tid * 8 + q;
    size_t i = (size_t)(b * kL + t) * kDPROJ;
    float rd = proj[i + COL_DT + g];
    float ra = proj[i + COL_A + g];
    float dt = rd > 20.f ? rd : log1pf(expf(rd));
    float al = -expf(ra) * dt;
    dtg[(size_t)(b * kL + t) * kG + g] = dt;
    sdt += (double)dt; loc_dt[q] = sdt;
    sal += (double)al; loc_al[q] = sal;
  }
  s_dt[tid] = sdt; s_al[tid] = sal;
  __syncthreads();
  for (int off = 1; off < 256; off <<= 1) {
    double a = 0.0, c = 0.0;
    if (tid >= off) { a = s_dt[tid - off]; c = s_al[tid - off]; }
    __syncthreads();
    s_dt[tid] += a; s_al[tid] += c;
    __syncthreads();
  }
  double base_dt = tid ? s_dt[tid - 1] : 0.0;
  double base_al = tid ? s_al[tid - 1] : 0.0;
#pragma unroll
  for (int q = 0; q < 8; ++q) {
    int t = tid * 8 + q;
    size_t idx = (size_t)(b * kL + t) * kG + g;
    cumdt[idx] = base_dt + loc_dt[q];
    cumalog[idx] = (float)(base_al + loc_al[q]);
  }
}

// ---------------- K2b: angle table — cos/sin per (tok, g, k)
__global__ __launch_bounds__(256) void k_angles(const double* __restrict__ cumdt,
                                                const float* __restrict__ theta_log,
                                                float* __restrict__ cs_tab) {
  int idx = blockIdx.x * 256 + threadIdx.x;  // kTOK * 128
  int tok = idx >> 7, gk = idx & 127, g = gk >> 5, k = gk & 31;
  double theta = exp((double)theta_log[g * 32 + k]);
  double ang = theta * cumdt[(size_t)tok * kG + g];
  const double twopi = 6.283185307179586476925286766559;
  double rem = ang - floor(ang / twopi) * twopi;
  cs_tab[(size_t)idx * 2] = cosf((float)rem);
  cs_tab[(size_t)idx * 2 + 1] = sinf((float)rem);
}

// ---------------- K3: RMS + bias + RoPE rotate of B/C, in place in proj
__global__ __launch_bounds__(256) void k_rotate(float* __restrict__ proj,
                                                const float* __restrict__ cs_tab,
                                                const float* __restrict__ normB_w,
                                                const float* __restrict__ normC_w,
                                                const float* __restrict__ bias_B,
                                                const float* __restrict__ bias_C) {
  int tok = blockIdx.x;
  int tid = threadIdx.x;
  __shared__ float buf[256];
  __shared__ float red[4];
  size_t rowoff = (size_t)tok * kDPROJ;
  int half = tid >> 7;      // 0 = B, 1 = C
  int j = tid & 127;        // j = n*2 + r
  int wave = tid >> 6;
  for (int g = 0; g < kG; ++g) {
    int col = (half ? COL_C : COL_B) + g * 128 + j;
    float v = proj[rowoff + col];
    float ss = v * v;
    for (int o = 1; o < 64; o <<= 1) ss += __shfl_xor(ss, o);
    if ((tid & 63) == 0) red[wave] = ss;
    __syncthreads();
    float tot = red[half * 2] + red[half * 2 + 1];
    float scale = rsqrtf(tot / 128.f + 1e-5f);
    const float* nw = half ? normC_w : normB_w;
    const float* bb = half ? bias_C : bias_B;
    float nv = v * scale * nw[j] + bb[g * 128 + j];
    buf[tid] = nv;
    __syncthreads();
    float other = buf[tid ^ 2];
    int n = j >> 1, k = n >> 1;
    bool isRe = (n & 1) == 0;
    const float* cs = cs_tab + (((size_t)tok * kG + g) * 32 + k) * 2;
    float cc = cs[0], sn = cs[1];
    float out = isRe ? (nv * cc - other * sn) : (other * sn + nv * cc);
    proj[rowoff + col] = out;
    __syncthreads();
  }
}

// ---------------- K4: xup Kron-MoE -> xmoe (B,L,H,128)
__global__ __launch_bounds__(256) void k_xup(const float* __restrict__ proj,
                                             const float* __restrict__ router,
                                             const float* __restrict__ Ae,
                                             const float* __restrict__ Be,
                                             const float* __restrict__ scale_,
                                             const float* __restrict__ bias_,
                                             float* __restrict__ xmoe) {
  int wave = threadIdx.x >> 6, lane = threadIdx.x & 63;
  int unit = blockIdx.x * 4 + wave;
  int tok = unit >> 4, h = unit & 15;
  __shared__ float xs_all[4][64];
  __shared__ float Rs[64][65];
  for (int m = threadIdx.x; m < 64 * 64; m += 256) Rs[m >> 6][m & 63] = router[m];
  float xv = proj[(size_t)tok * kDPROJ + COL_XP + h * 64 + lane];
  xs_all[wave][lane] = xv;
  __syncthreads();
  const float* xs = xs_all[wave];
  double accd = 0.0;
#pragma unroll
  for (int d = 0; d < 64; ++d) accd += (double)Rs[lane][d] * (double)xs[d];
  float logit = (float)accd;
  float v1 = logit; int i1 = lane;
  for (int o = 1; o < 64; o <<= 1) {
    float vv = __shfl_xor(v1, o); int ii = __shfl_xor(i1, o);
    if (vv > v1 || (vv == v1 && ii < i1)) { v1 = vv; i1 = ii; }
  }
  float lm = (lane == i1) ? -INFINITY : logit;
  float v2 = lm; int i2 = lane;
  for (int o = 1; o < 64; o <<= 1) {
    float vv = __shfl_xor(v2, o); int ii = __shfl_xor(i2, o);
    if (vv > v2 || (vv == v2 && ii < i2)) { v2 = vv; i2 = ii; }
  }
  float e12 = expf(v2 - v1);
  float p1 = 1.f / (1.f + e12), p2 = e12 / (1.f + e12);
  float out0 = 0.f, out1 = 0.f;
#pragma unroll
  for (int kk = 0; kk < 2; ++kk) {
    int e = kk ? i2 : i1;
    float pw = kk ? p2 : p1;
    const float* A = Ae + (size_t)e * 64;    // 8x8
    const float* Bm = Be + (size_t)e * 128;  // 16x8
#pragma unroll
    for (int hlf = 0; hlf < 2; ++hlf) {
      int c = lane + hlf * 64;
      int o = c >> 4, p = c & 15;
      float y = 0.f;
#pragma unroll
      for (int i = 0; i < 8; ++i) {
        float t = 0.f;
#pragma unroll
        for (int jj = 0; jj < 8; ++jj) t += xs[i * 8 + jj] * Bm[p * 8 + jj];
        y += A[o * 8 + i] * t;
      }
      if (hlf) out1 += pw * y; else out0 += pw * y;
    }
  }
  float sc = scale_[0];
  size_t ob = (size_t)unit * 128;
  xmoe[ob + lane] = out0 * sc + bias_[lane];
  xmoe[ob + lane + 64] = out1 * sc + bias_[lane + 64];
}

// ---------------- K5: pass A — per-chunk local end state S_c
__global__ __launch_bounds__(256) void k_passA(const float* __restrict__ proj,
                                               const float* __restrict__ xmoe,
                                               const float* __restrict__ dtg,
                                               const float* __restrict__ cumalog,
                                               float* __restrict__ hstate) {
  int bid = blockIdx.x;
  int c = bid & 31, h = (bid >> 5) & 15, b = bid >> 9, g = h >> 2;
  int tid = threadIdx.x;
  __shared__ float Bs[128][65];
  __shared__ float Xs[128][65];
  __shared__ float wv[64];
  int base = c * 64;
  size_t tok0 = (size_t)b * kL + base;
  if (tid < 64) {
    float ca_last = cumalog[(tok0 + 63) * kG + g];
    float ca_s = cumalog[(tok0 + tid) * kG + g];
    float dt = dtg[(tok0 + tid) * kG + g];
    wv[tid] = expf(ca_last - ca_s) * dt;
  }
  __syncthreads();
  for (int m = tid; m < 8192; m += 256) {
    int s = m >> 7, j = m & 127;
    float bval = proj[(tok0 + s) * kDPROJ + COL_B + g * 128 + j];
    Bs[s * 2 + (j & 1)][j >> 1] = bval * wv[s];
    float xval = xmoe[((tok0 + s) * kH + h) * (size_t)128 + j];
    Xs[s * 2 + (j & 1)][j >> 1] = xval;
  }
  __syncthreads();
  int tx = tid & 15, ty = tid >> 4;
  float acc[4][4];
#pragma unroll
  for (int i = 0; i < 4; ++i)
#pragma unroll
    for (int j = 0; j < 4; ++j) acc[i][j] = 0.f;
  for (int k = 0; k < 128; ++k) {
    float a[4], bv[4];
#pragma unroll
    for (int q = 0; q < 4; ++q) a[q] = Bs[k][ty * 4 + q];
#pragma unroll
    for (int q = 0; q < 4; ++q) bv[q] = Xs[k][tx * 4 + q];
#pragma unroll
    for (int i = 0; i < 4; ++i)
#pragma unroll
      for (int j = 0; j < 4; ++j) acc[i][j] += a[i] * bv[j];
  }
  float* out = hstate + (size_t)bid * 4096;
#pragma unroll
  for (int i = 0; i < 4; ++i)
#pragma unroll
    for (int j = 0; j < 4; ++j)
      out[(ty * 4 + i) * 64 + tx * 4 + j] = acc[i][j];
}

// ---------------- K6: pass B — sequential inter-chunk combine
__global__ __launch_bounds__(256) void k_passB(float* __restrict__ hstate,
                                               const float* __restrict__ cumalog) {
  int bh = blockIdx.x;
  int b = bh >> 4, h = bh & 15, g = h >> 2;
  int tid = threadIdx.x;
  float hrun[16];
#pragma unroll
  for (int q = 0; q < 16; ++q) hrun[q] = 0.f;
  float* Hbase = hstate + (size_t)bh * 32 * 4096;
  for (int c = 0; c < 32; ++c) {
    float ca_last = cumalog[((size_t)b * kL + c * 64 + 63) * kG + g];
    float ca_prev = c ? cumalog[((size_t)b * kL + c * 64 - 1) * kG + g] : 0.f;
    float Dc = expf(ca_last - ca_prev);
    float* Hc = Hbase + (size_t)c * 4096;
#pragma unroll
    for (int q = 0; q < 16; ++q) {
      int idx = tid + q * 256;
      float local = Hc[idx];
      Hc[idx] = hrun[q];
      hrun[q] = Dc * hrun[q] + local;
    }
  }
}

// ---------------- K7: pass C — chunk outputs + fused ydown -> d_out (y1)
__global__ __launch_bounds__(256) void k_passC(const float* __restrict__ proj,
                                               const float* __restrict__ xmoe,
                                               const float* __restrict__ dtg,
                                               const float* __restrict__ cumalog,
                                               const float* __restrict__ hstate,
                                               const float* __restrict__ ydown,
                                               float* __restrict__ outY) {
  int bid = blockIdx.x;
  int c = bid & 31, h = (bid >> 5) & 15, b = bid >> 9, g = h >> 2;
  int tid = threadIdx.x;
  __shared__ float Cs[128][65];
  __shared__ float Bs[128][65];
  __shared__ float Gs[128][129];
  __shared__ float ell[64], dts[64], elx[64];
  int base = c * 64;
  size_t tok0 = (size_t)b * kL + base;
  if (tid < 64) {
    float ca_prev = base ? cumalog[(tok0 - 1) * kG + g] : 0.f;
    float ca_t = cumalog[(tok0 + tid) * kG + g];
    ell[tid] = ca_t - ca_prev;
    elx[tid] = expf(ca_t - ca_prev);
    dts[tid] = dtg[(tok0 + tid) * kG + g];
  }
  for (int m = tid; m < 8192; m += 256) {
    int s = m >> 7, j = m & 127;
    Cs[s * 2 + (j & 1)][j >> 1] = proj[(tok0 + s) * kDPROJ + COL_C + g * 128 + j];
    Bs[s * 2 + (j & 1)][j >> 1] = proj[(tok0 + s) * kDPROJ + COL_B + g * 128 + j];
  }
  __syncthreads();
  {
    int tx = tid & 15, ty = tid >> 4;
    float acc[8][8];
#pragma unroll
    for (int i = 0; i < 8; ++i)
#pragma unroll
      for (int j = 0; j < 8; ++j) acc[i][j] = 0.f;
    for (int n = 0; n < 64; ++n) {
      float a[8], bv[8];
#pragma unroll
      for (int q = 0; q < 8; ++q) a[q] = Cs[ty * 8 + q][n];
#pragma unroll
      for (int q = 0; q < 8; ++q) bv[q] = Bs[tx * 8 + q][n];
#pragma unroll
      for (int i = 0; i < 8; ++i)
#pragma unroll
        for (int j = 0; j < 8; ++j) acc[i][j] += a[i] * bv[j];
    }
#pragma unroll
    for (int i = 0; i < 8; ++i) {
      int row = ty * 8 + i, t = row >> 1;
#pragma unroll
      for (int j = 0; j < 8; ++j) {
        int col = tx * 8 + j, s = col >> 1;
        float w = (s <= t) ? dts[s] * expf(ell[t] - ell[s]) : 0.f;
        Gs[row][col] = acc[i][j] * w;
      }
    }
  }
  __syncthreads();
  for (int m = tid; m < 4096; m += 256)
    Bs[m >> 6][m & 63] = hstate[(size_t)bid * 4096 + m];
  __syncthreads();
  int tx8 = tid & 7, ty32 = tid >> 3;
  float yac[4][8];
#pragma unroll
  for (int i = 0; i < 4; ++i)
#pragma unroll
    for (int j = 0; j < 8; ++j) yac[i][j] = 0.f;
  for (int n = 0; n < 64; ++n) {
    float a[4], bv[8];
#pragma unroll
    for (int q = 0; q < 4; ++q) a[q] = Cs[ty32 * 4 + q][n];
#pragma unroll
    for (int q = 0; q < 8; ++q) bv[q] = Bs[n][tx8 * 8 + q];
#pragma unroll
    for (int i = 0; i < 4; ++i)
#pragma unroll
      for (int j = 0; j < 8; ++j) yac[i][j] += a[i] * bv[j];
  }
#pragma unroll
  for (int i = 0; i < 4; ++i) {
    float e = elx[(ty32 * 4 + i) >> 1];
#pragma unroll
    for (int j = 0; j < 8; ++j) yac[i][j] *= e;
  }
  __syncthreads();
  for (int m = tid; m < 8192; m += 256) {
    int s = m >> 7, j = m & 127;
    Cs[s * 2 + (j & 1)][j >> 1] = xmoe[((tok0 + s) * kH + h) * (size_t)128 + j];
  }
  __syncthreads();
  for (int k = 0; k < 128; ++k) {
    float a[4], bv[8];
#pragma unroll
    for (int q = 0; q < 4; ++q) a[q] = Gs[ty32 * 4 + q][k];
#pragma unroll
    for (int q = 0; q < 8; ++q) bv[q] = Cs[k][tx8 * 8 + q];
#pragma unroll
    for (int i = 0; i < 4; ++i)
#pragma unroll
      for (int j = 0; j < 8; ++j) yac[i][j] += a[i] * bv[j];
  }
  __syncthreads();
#pragma unroll
  for (int i = 0; i < 4; ++i) {
    int row = ty32 * 4 + i, t = row >> 1, r = row & 1;
#pragma unroll
    for (int j = 0; j < 8; ++j) {
      int p = tx8 * 8 + j;
      Gs[t][p * 2 + r] = yac[i][j];
    }
  }
  for (int m = tid; m < 8192; m += 256) {
    int o = m >> 7, cc = m & 127;
    Bs[cc][o] = ydown[m];
  }
  __syncthreads();
  {
    int tx = tid & 15, ty = tid >> 4;
    float oc[4][4];
#pragma unroll
    for (int i = 0; i < 4; ++i)
#pragma unroll
      for (int j = 0; j < 4; ++j) oc[i][j] = 0.f;
    for (int cc = 0; cc < 128; ++cc) {
      float a[4], bv[4];
#pragma unroll
      for (int q = 0; q < 4; ++q) a[q] = Gs[ty * 4 + q][cc];
#pragma unroll
      for (int q = 0; q < 4; ++q) bv[q] = Bs[cc][tx * 4 + q];
#pragma unroll
      for (int i = 0; i < 4; ++i)
#pragma unroll
        for (int j = 0; j < 4; ++j) oc[i][j] += a[i] * bv[j];
    }
#pragma unroll
    for (int i = 0; i < 4; ++i) {
      int t = ty * 4 + i;
#pragma unroll
      for (int j = 0; j < 4; ++j) {
        int o = tx * 4 + j;
        outY[(tok0 + t) * (size_t)1024 + h * 64 + o] = oc[i][j];
      }
    }
  }
}

// ---------------- K8: gate
__global__ __launch_bounds__(256) void k_gate(float* __restrict__ y,
                                              const float* __restrict__ proj,
                                              const float* __restrict__ Dv,
                                              const float* __restrict__ pregate_w) {
  int tok = blockIdx.x;
  int tid = threadIdx.x;
  size_t yoff = (size_t)tok * 1024;
  size_t poff = (size_t)tok * kDPROJ;
  __shared__ float red[4];
  float vals[4];
  float ss = 0.f;
#pragma unroll
  for (int q = 0; q < 4; ++q) {
    int j = tid + q * 256;
    float v = y[yoff + j] + proj[poff + COL_XP + j] * Dv[j >> 6];
    vals[q] = v;
    ss += v * v;
  }
  for (int o = 1; o < 64; o <<= 1) ss += __shfl_xor(ss, o);
  if ((tid & 63) == 0) red[tid >> 6] = ss;
  __syncthreads();
  float tot = red[0] + red[1] + red[2] + red[3];
  float scale = rsqrtf(tot / 1024.f + 1e-5f);
#pragma unroll
  for (int q = 0; q < 4; ++q) {
    int j = tid + q * 256;
    float z = proj[poff + COL_Z + j];
    float sig = 1.f / (1.f + expf(-z));
    y[yoff + j] = vals[q] * scale * pregate_w[j] * sig;
  }
}

// ---------------- K9: oup Kron-MoE, in place on d_out
__global__ __launch_bounds__(256) void k_oup(float* __restrict__ y,
                                             const float* __restrict__ router,
                                             const float* __restrict__ Ae,
                                             const float* __restrict__ Be,
                                             const float* __restrict__ scale_,
                                             const float* __restrict__ bias_) {
  int tok = blockIdx.x;
  int tid = threadIdx.x;
  __shared__ float xs[1024];
  __shared__ float Ts[32][33];
  __shared__ float logits_s[64];
  __shared__ double partial[256];
  size_t yoff = (size_t)tok * 1024;
  for (int m = tid; m < 1024; m += 256) xs[m] = y[yoff + m];
  __syncthreads();
  {
    int e = tid & 63, q = tid >> 6;
    double acc = 0.0;
    const float* rw = router + (size_t)e * 1024 + q * 256;
    const float* xv = xs + q * 256;
    for (int d = 0; d < 256; ++d) acc += (double)rw[d] * (double)xv[d];
    partial[tid] = acc;
  }
  __syncthreads();
  if (tid < 64) {
    double l = partial[tid] + partial[tid + 64] + partial[tid + 128] + partial[tid + 192];
    logits_s[tid] = (float)l;
  }
  __syncthreads();
  float v1 = -INFINITY; int i1 = -1;
  for (int e = 0; e < 64; ++e) { float v = logits_s[e]; if (v > v1) { v1 = v; i1 = e; } }
  float v2 = -INFINITY; int i2 = -1;
  for (int e = 0; e < 64; ++e) { if (e == i1) continue; float v = logits_s[e]; if (v > v2) { v2 = v; i2 = e; } }
  float e12 = expf(v2 - v1);
  float p1 = 1.f / (1.f + e12), p2 = e12 / (1.f + e12);
  float out[4] = {0.f, 0.f, 0.f, 0.f};
  for (int kk = 0; kk < 2; ++kk) {
    int e = kk ? i2 : i1;
    float pw = kk ? p2 : p1;
    const float* A = Ae + (size_t)e * 1024;
    const float* Bm = Be + (size_t)e * 1024;
    __syncthreads();
    for (int m = tid; m < 1024; m += 256) {
      int i = m >> 5, p = m & 31;
      float t = 0.f;
#pragma unroll
      for (int j = 0; j < 32; ++j) t += xs[i * 32 + j] * Bm[p * 32 + j];
      Ts[i][p] = t;
    }
    __syncthreads();
#pragma unroll
    for (int q = 0; q < 4; ++q) {
      int cc = tid + q * 256;
      int o = cc >> 5, p = cc & 31;
      float a2 = 0.f;
#pragma unroll
      for (int i = 0; i < 32; ++i) a2 += A[o * 32 + i] * Ts[i][p];
      out[q] += pw * a2;
    }
  }
  float sc = scale_[0];
#pragma unroll
  for (int q = 0; q < 4; ++q) {
    int cc = tid + q * 256;
    y[yoff + cc] = out[q] * sc + bias_[cc];
  }
}

extern "C" void kernel_launch(void* const* d_in, const int* in_sizes, int n_in,
                              void* d_out, int out_size, void* d_ws, size_t ws_size,
                              hipStream_t stream) {
  const float* u          = (const float*)d_in[0];
  const float* in_proj_w  = (const float*)d_in[1];
  const float* in_proj_b  = (const float*)d_in[2];
  const float* xup_router = (const float*)d_in[3];
  const float* xup_A      = (const float*)d_in[4];
  const float* xup_B      = (const float*)d_in[5];
  const float* xup_scale  = (const float*)d_in[6];
  const float* xup_bias   = (const float*)d_in[7];
  const float* ydown_w    = (const float*)d_in[8];
  const float* oup_router = (const float*)d_in[9];
  const float* oup_A      = (const float*)d_in[10];
  const float* oup_B      = (const float*)d_in[11];
  const float* oup_scale  = (const float*)d_in[12];
  const float* oup_bias   = (const float*)d_in[13];
  const float* theta_log  = (const float*)d_in[14];
  const float* Dv         = (const float*)d_in[15];
  const float* normB_w    = (const float*)d_in[16];
  const float* normC_w    = (const float*)d_in[17];
  const float* bias_B     = (const float*)d_in[18];
  const float* bias_C     = (const float*)d_in[19];
  const float* pregate_w  = (const float*)d_in[20];

  char* ws = (char*)d_ws;
  float* proj = (float*)ws;      ws += (size_t)kTOK * kDPROJ * 4;        // 101.06 MB
  float* dtg = (float*)ws;       ws += (size_t)kTOK * kG * 4;
  float* cumalog = (float*)ws;   ws += (size_t)kTOK * kG * 4;
  double* cumdt = (double*)ws;   ws += (size_t)kTOK * kG * 8;
  float* cs_tab = (float*)ws;    ws += (size_t)kTOK * kG * 32 * 2 * 4;   // 8.39 MB
  float* xmoe = (float*)ws;      ws += (size_t)kTOK * kH * 128 * 4;      // 67.1 MB
  float* hstate = (float*)ws;    ws += (size_t)kB * kH * kNC * 4096 * 4; // 33.55 MB
  float* outY = (float*)d_out;

  // bf16 split staging aliases the (not-yet-written) xmoe region
  unsigned short* Uhi = (unsigned short*)xmoe;
  unsigned short* Ulo = Uhi + (size_t)kTOK * kDM;
  unsigned short* Whi = Ulo + (size_t)kTOK * kDM;
  unsigned short* Wlo = Whi + (size_t)kNPAD * kDM;

  k_split_u<<<dim3(kTOK * kDM / 4 / 256), dim3(256), 0, stream>>>(u, Uhi, Ulo);
  k_split_w<<<dim3(kNPAD * kDM / 4 / 256), dim3(256), 0, stream>>>(in_proj_w, Whi, Wlo);
  k_inproj_mfma<<<dim3(kTOK / 128, kNPAD / 128), dim3(256), 0, stream>>>(Uhi, Ulo, Whi, Wlo, in_proj_b, proj);
  k_dtprep<<<dim3(kB * kG), dim3(256), 0, stream>>>(proj, dtg, cumalog, cumdt);
  k_angles<<<dim3(kTOK * 128 / 256), dim3(256), 0, stream>>>(cumdt, theta_log, cs_tab);
  k_rotate<<<dim3(kTOK), dim3(256), 0, stream>>>(proj, cs_tab, normB_w, normC_w, bias_B, bias_C);
  k_xup<<<dim3(kTOK * kH / 4), dim3(256), 0, stream>>>(proj, xup_router, xup_A, xup_B, xup_scale, xup_bias, xmoe);
  k_passA<<<dim3(kB * kH * kNC), dim3(256), 0, stream>>>(proj, xmoe, dtg, cumalog, hstate);
  k_passB<<<dim3(kB * kH), dim3(256), 0, stream>>>(hstate, cumalog);
  k_passC<<<dim3(kB * kH * kNC), dim3(256), 0, stream>>>(proj, xmoe, dtg, cumalog, hstate, ydown_w, outY);
  k_gate<<<dim3(kTOK), dim3(256), 0, stream>>>(outY, proj, Dv, pregate_w);
  k_oup<<<dim3(kTOK), dim3(256), 0, stream>>>(outY, oup_router, oup_A, oup_B, oup_scale, oup_bias);
}

// Round 3
// 1061.357 us; speedup vs baseline: 1.8840x; 1.1151x over previous
//
#include <hip/hip_runtime.h>
#include <hip/hip_bf16.h>
#include <math.h>

namespace {
constexpr int kB = 4, kL = 2048, kDM = 1024;
constexpr int kH = 16, kG = 4;
constexpr int kDPROJ = 3084;
constexpr int COL_Z = 0, COL_XP = 1024, COL_B = 2048, COL_C = 2560, COL_DT = 3072, COL_A = 3076;
constexpr int kTOK = kB * kL;           // 8192
constexpr int kNC = kL / 64;            // 32 chunks
constexpr int kNPAD = 3200;             // W padded rows (25 * 128)
constexpr float kLOG2E = 1.4426950408889634f;
}

typedef __attribute__((ext_vector_type(8))) __bf16 bf16x8;
typedef __attribute__((ext_vector_type(8))) unsigned short u16x8;
typedef __attribute__((ext_vector_type(4))) float f32x4;

#define GLDS16(gp, lp)                                                          \
  __builtin_amdgcn_global_load_lds(                                             \
      (const __attribute__((address_space(1))) void*)(gp),                      \
      (__attribute__((address_space(3))) void*)(lp), 16, 0, 0)

__device__ __forceinline__ unsigned short bf16_rne(float f) {
  unsigned u = __builtin_bit_cast(unsigned, f);
  unsigned r = u + 0x7fffu + ((u >> 16) & 1u);
  return (unsigned short)(r >> 16);
}
__device__ __forceinline__ void split2(float f, unsigned short& h, unsigned short& l) {
  unsigned short hh = bf16_rne(f);
  float hf = __builtin_bit_cast(float, (unsigned)hh << 16);
  h = hh;
  l = bf16_rne(f - hf);
}
__device__ __forceinline__ bf16x8 ldsb8(const unsigned short* p) {
  return __builtin_bit_cast(bf16x8, *(const u16x8*)p);
}

// ---------------- K0a: split U -> (hi, lo) bf16
__global__ __launch_bounds__(256) void k_split_u(const float* __restrict__ X,
                                                 unsigned short* __restrict__ hi,
                                                 unsigned short* __restrict__ lo) {
  int i = blockIdx.x * 256 + threadIdx.x;
  float4 x = ((const float4*)X)[i];
  float xs[4] = {x.x, x.y, x.z, x.w};
  ushort4 hv, lv;
  unsigned short hq[4], lq[4];
#pragma unroll
  for (int q = 0; q < 4; ++q) split2(xs[q], hq[q], lq[q]);
  hv.x = hq[0]; hv.y = hq[1]; hv.z = hq[2]; hv.w = hq[3];
  lv.x = lq[0]; lv.y = lq[1]; lv.z = lq[2]; lv.w = lq[3];
  ((ushort4*)hi)[i] = hv;
  ((ushort4*)lo)[i] = lv;
}

// ---------------- K0b: split W -> (hi, lo) bf16, padded to kNPAD rows
__global__ __launch_bounds__(256) void k_split_w(const float* __restrict__ X,
                                                 unsigned short* __restrict__ hi,
                                                 unsigned short* __restrict__ lo) {
  int i = blockIdx.x * 256 + threadIdx.x;
  int row = i >> 8;
  float4 x = make_float4(0.f, 0.f, 0.f, 0.f);
  if (row < kDPROJ) x = ((const float4*)X)[i];
  float xs[4] = {x.x, x.y, x.z, x.w};
  ushort4 hv, lv;
  unsigned short hq[4], lq[4];
#pragma unroll
  for (int q = 0; q < 4; ++q) split2(xs[q], hq[q], lq[q]);
  hv.x = hq[0]; hv.y = hq[1]; hv.z = hq[2]; hv.w = hq[3];
  lv.x = lq[0]; lv.y = lq[1]; lv.z = lq[2]; lv.w = lq[3];
  ((ushort4*)hi)[i] = hv;
  ((ushort4*)lo)[i] = lv;
}

// ---------------- K1: in_proj GEMM via split-bf16 MFMA
__global__ __launch_bounds__(256) void k_inproj_mfma(
    const unsigned short* __restrict__ Uhi, const unsigned short* __restrict__ Ulo,
    const unsigned short* __restrict__ Whi, const unsigned short* __restrict__ Wlo,
    const float* __restrict__ bias, float* __restrict__ proj) {
  __shared__ unsigned short lds_u[16384];
  const int tid = threadIdx.x;
  const int wave = tid >> 6, lane = tid & 63;
  const int wm = wave >> 1, wn = wave & 1;
  const int row0 = blockIdx.x * 128, col0 = blockIdx.y * 128;
  const int fr = lane & 15, kq = lane >> 4;

  f32x4 acc[4][4];
#pragma unroll
  for (int i = 0; i < 4; ++i)
#pragma unroll
    for (int j = 0; j < 4; ++j) acc[i][j] = (f32x4){0.f, 0.f, 0.f, 0.f};

  const int s0 = wave * 64 + lane;

  for (int k0 = 0; k0 < kDM; k0 += 32) {
#pragma unroll
    for (int q = 0; q < 2; ++q) {
      const int slot = q * 256 + s0;
      const int r = slot >> 2;
      const int ce = ((slot & 3) ^ ((r >> 1) & 3)) * 8;
      const size_t ao = (size_t)(row0 + r) * kDM + k0 + ce;
      const size_t bo = (size_t)(col0 + r) * kDM + k0 + ce;
      const int lb = (q * 256 + wave * 64) * 16;
      GLDS16(Uhi + ao, (char*)lds_u + lb);
      GLDS16(Ulo + ao, (char*)lds_u + 8192 + lb);
      GLDS16(Whi + bo, (char*)lds_u + 16384 + lb);
      GLDS16(Wlo + bo, (char*)lds_u + 24576 + lb);
    }
    __syncthreads();
    bf16x8 ahi[4], alo[4], bhi[4], blo[4];
#pragma unroll
    for (int mi = 0; mi < 4; ++mi) {
      int r = wm * 64 + mi * 16 + fr;
      int off = r * 32 + ((kq ^ ((r >> 1) & 3)) * 8);
      ahi[mi] = ldsb8(lds_u + off);
      alo[mi] = ldsb8(lds_u + 4096 + off);
    }
#pragma unroll
    for (int ni = 0; ni < 4; ++ni) {
      int r = wn * 64 + ni * 16 + fr;
      int off = r * 32 + ((kq ^ ((r >> 1) & 3)) * 8);
      bhi[ni] = ldsb8(lds_u + 8192 + off);
      blo[ni] = ldsb8(lds_u + 12288 + off);
    }
#pragma unroll
    for (int mi = 0; mi < 4; ++mi)
#pragma unroll
      for (int ni = 0; ni < 4; ++ni) {
        acc[mi][ni] = __builtin_amdgcn_mfma_f32_16x16x32_bf16(ahi[mi], bhi[ni], acc[mi][ni], 0, 0, 0);
        acc[mi][ni] = __builtin_amdgcn_mfma_f32_16x16x32_bf16(ahi[mi], blo[ni], acc[mi][ni], 0, 0, 0);
        acc[mi][ni] = __builtin_amdgcn_mfma_f32_16x16x32_bf16(alo[mi], bhi[ni], acc[mi][ni], 0, 0, 0);
      }
    __syncthreads();
  }

  const int orow = row0 + wm * 64, ocol = col0 + wn * 64;
#pragma unroll
  for (int mi = 0; mi < 4; ++mi)
#pragma unroll
    for (int ni = 0; ni < 4; ++ni) {
      int cg = ocol + ni * 16 + fr;
      if (cg < kDPROJ) {
        float bv = bias[cg];
#pragma unroll
        for (int r = 0; r < 4; ++r) {
          int rg = orow + mi * 16 + kq * 4 + r;
          proj[(size_t)rg * kDPROJ + cg] = acc[mi][ni][r] + bv;
        }
      }
    }
}

// ---------------- K2: dt prep + f64 scans
__global__ __launch_bounds__(256) void k_dtprep(const float* __restrict__ proj,
                                                float* __restrict__ dtg,
                                                float* __restrict__ cumalog,
                                                double* __restrict__ cumdt) {
  int bg = blockIdx.x;
  int b = bg / kG, g = bg % kG;
  int tid = threadIdx.x;
  __shared__ double s_dt[256], s_al[256];
  double loc_dt[8], loc_al[8];
  double sdt = 0.0, sal = 0.0;
#pragma unroll
  for (int q = 0; q < 8; ++q) {
    int t = tid * 8 + q;
    size_t i = (size_t)(b * kL + t) * kDPROJ;
    float rd = proj[i + COL_DT + g];
    float ra = proj[i + COL_A + g];
    float dt = rd > 20.f ? rd : log1pf(expf(rd));
    float al = -expf(ra) * dt;
    dtg[(size_t)(b * kL + t) * kG + g] = dt;
    sdt += (double)dt; loc_dt[q] = sdt;
    sal += (double)al; loc_al[q] = sal;
  }
  s_dt[tid] = sdt; s_al[tid] = sal;
  __syncthreads();
  for (int off = 1; off < 256; off <<= 1) {
    double a = 0.0, c = 0.0;
    if (tid >= off) { a = s_dt[tid - off]; c = s_al[tid - off]; }
    __syncthreads();
    s_dt[tid] += a; s_al[tid] += c;
    __syncthreads();
  }
  double base_dt = tid ? s_dt[tid - 1] : 0.0;
  double base_al = tid ? s_al[tid - 1] : 0.0;
#pragma unroll
  for (int q = 0; q < 8; ++q) {
    int t = tid * 8 + q;
    size_t idx = (size_t)(b * kL + t) * kG + g;
    cumdt[idx] = base_dt + loc_dt[q];
    cumalog[idx] = (float)(base_al + loc_al[q]);
  }
}

// ---------------- K2b: angle table
__global__ __launch_bounds__(256) void k_angles(const double* __restrict__ cumdt,
                                                const float* __restrict__ theta_log,
                                                float* __restrict__ cs_tab) {
  int idx = blockIdx.x * 256 + threadIdx.x;
  int tok = idx >> 7, gk = idx & 127, g = gk >> 5, k = gk & 31;
  double theta = exp((double)theta_log[g * 32 + k]);
  double ang = theta * cumdt[(size_t)tok * kG + g];
  const double twopi = 6.283185307179586476925286766559;
  double rem = ang - floor(ang / twopi) * twopi;
  cs_tab[(size_t)idx * 2] = cosf((float)rem);
  cs_tab[(size_t)idx * 2 + 1] = sinf((float)rem);
}

// ---------------- K3: RMS + bias + RoPE rotate of B/C, in place in proj
__global__ __launch_bounds__(256) void k_rotate(float* __restrict__ proj,
                                                const float* __restrict__ cs_tab,
                                                const float* __restrict__ normB_w,
                                                const float* __restrict__ normC_w,
                                                const float* __restrict__ bias_B,
                                                const float* __restrict__ bias_C) {
  int tok = blockIdx.x;
  int tid = threadIdx.x;
  __shared__ float buf[256];
  __shared__ float red[4];
  size_t rowoff = (size_t)tok * kDPROJ;
  int half = tid >> 7;
  int j = tid & 127;
  int wave = tid >> 6;
  for (int g = 0; g < kG; ++g) {
    int col = (half ? COL_C : COL_B) + g * 128 + j;
    float v = proj[rowoff + col];
    float ss = v * v;
    for (int o = 1; o < 64; o <<= 1) ss += __shfl_xor(ss, o);
    if ((tid & 63) == 0) red[wave] = ss;
    __syncthreads();
    float tot = red[half * 2] + red[half * 2 + 1];
    float scale = rsqrtf(tot / 128.f + 1e-5f);
    const float* nw = half ? normC_w : normB_w;
    const float* bb = half ? bias_C : bias_B;
    float nv = v * scale * nw[j] + bb[g * 128 + j];
    buf[tid] = nv;
    __syncthreads();
    float other = buf[tid ^ 2];
    int n = j >> 1, k = n >> 1;
    bool isRe = (n & 1) == 0;
    const float* cs = cs_tab + (((size_t)tok * kG + g) * 32 + k) * 2;
    float cc = cs[0], sn = cs[1];
    float out = isRe ? (nv * cc - other * sn) : (other * sn + nv * cc);
    proj[rowoff + col] = out;
    __syncthreads();
  }
}

// ---------------- K4: xup Kron-MoE -> xmoe (B,L,H,128)
__global__ __launch_bounds__(256) void k_xup(const float* __restrict__ proj,
                                             const float* __restrict__ router,
                                             const float* __restrict__ Ae,
                                             const float* __restrict__ Be,
                                             const float* __restrict__ scale_,
                                             const float* __restrict__ bias_,
                                             float* __restrict__ xmoe) {
  int wave = threadIdx.x >> 6, lane = threadIdx.x & 63;
  int unit = blockIdx.x * 4 + wave;
  int tok = unit >> 4, h = unit & 15;
  __shared__ float xs_all[4][64];
  __shared__ float Rs[64][65];
  for (int m = threadIdx.x; m < 64 * 64; m += 256) Rs[m >> 6][m & 63] = router[m];
  float xv = proj[(size_t)tok * kDPROJ + COL_XP + h * 64 + lane];
  xs_all[wave][lane] = xv;
  __syncthreads();
  const float* xs = xs_all[wave];
  double accd = 0.0;
#pragma unroll
  for (int d = 0; d < 64; ++d) accd += (double)Rs[lane][d] * (double)xs[d];
  float logit = (float)accd;
  float v1 = logit; int i1 = lane;
  for (int o = 1; o < 64; o <<= 1) {
    float vv = __shfl_xor(v1, o); int ii = __shfl_xor(i1, o);
    if (vv > v1 || (vv == v1 && ii < i1)) { v1 = vv; i1 = ii; }
  }
  float lm = (lane == i1) ? -INFINITY : logit;
  float v2 = lm; int i2 = lane;
  for (int o = 1; o < 64; o <<= 1) {
    float vv = __shfl_xor(v2, o); int ii = __shfl_xor(i2, o);
    if (vv > v2 || (vv == v2 && ii < i2)) { v2 = vv; i2 = ii; }
  }
  float e12 = expf(v2 - v1);
  float p1 = 1.f / (1.f + e12), p2 = e12 / (1.f + e12);
  float out0 = 0.f, out1 = 0.f;
#pragma unroll
  for (int kk = 0; kk < 2; ++kk) {
    int e = kk ? i2 : i1;
    float pw = kk ? p2 : p1;
    const float* A = Ae + (size_t)e * 64;
    const float* Bm = Be + (size_t)e * 128;
#pragma unroll
    for (int hlf = 0; hlf < 2; ++hlf) {
      int c = lane + hlf * 64;
      int o = c >> 4, p = c & 15;
      float y = 0.f;
#pragma unroll
      for (int i = 0; i < 8; ++i) {
        float t = 0.f;
#pragma unroll
        for (int jj = 0; jj < 8; ++jj) t += xs[i * 8 + jj] * Bm[p * 8 + jj];
        y += A[o * 8 + i] * t;
      }
      if (hlf) out1 += pw * y; else out0 += pw * y;
    }
  }
  float sc = scale_[0];
  size_t ob = (size_t)unit * 128;
  xmoe[ob + lane] = out0 * sc + bias_[lane];
  xmoe[ob + lane + 64] = out1 * sc + bias_[lane + 64];
}

// ---------------- K5: pass A — per-chunk local end state S_c
__global__ __launch_bounds__(256) void k_passA(const float* __restrict__ proj,
                                               const float* __restrict__ xmoe,
                                               const float* __restrict__ dtg,
                                               const float* __restrict__ cumalog,
                                               float* __restrict__ hstate) {
  int bid = blockIdx.x;
  int c = bid & 31, h = (bid >> 5) & 15, b = bid >> 9, g = h >> 2;
  int tid = threadIdx.x;
  __shared__ float Bs[128][65];
  __shared__ float Xs[128][65];
  __shared__ float wv[64];
  int base = c * 64;
  size_t tok0 = (size_t)b * kL + base;
  if (tid < 64) {
    float ca_last = cumalog[(tok0 + 63) * kG + g];
    float ca_s = cumalog[(tok0 + tid) * kG + g];
    float dt = dtg[(tok0 + tid) * kG + g];
    wv[tid] = expf(ca_last - ca_s) * dt;
  }
  __syncthreads();
  for (int m = tid; m < 8192; m += 256) {
    int s = m >> 7, j = m & 127;
    float bval = proj[(tok0 + s) * kDPROJ + COL_B + g * 128 + j];
    Bs[s * 2 + (j & 1)][j >> 1] = bval * wv[s];
    float xval = xmoe[((tok0 + s) * kH + h) * (size_t)128 + j];
    Xs[s * 2 + (j & 1)][j >> 1] = xval;
  }
  __syncthreads();
  int tx = tid & 15, ty = tid >> 4;
  float acc[4][4];
#pragma unroll
  for (int i = 0; i < 4; ++i)
#pragma unroll
    for (int j = 0; j < 4; ++j) acc[i][j] = 0.f;
  for (int k = 0; k < 128; ++k) {
    float a[4], bv[4];
#pragma unroll
    for (int q = 0; q < 4; ++q) a[q] = Bs[k][ty * 4 + q];
#pragma unroll
    for (int q = 0; q < 4; ++q) bv[q] = Xs[k][tx * 4 + q];
#pragma unroll
    for (int i = 0; i < 4; ++i)
#pragma unroll
      for (int j = 0; j < 4; ++j) acc[i][j] += a[i] * bv[j];
  }
  float* out = hstate + (size_t)bid * 4096;
#pragma unroll
  for (int i = 0; i < 4; ++i)
#pragma unroll
    for (int j = 0; j < 4; ++j)
      out[(ty * 4 + i) * 64 + tx * 4 + j] = acc[i][j];
}

// ---------------- K6: pass B — sequential inter-chunk combine
__global__ __launch_bounds__(256) void k_passB(float* __restrict__ hstate,
                                               const float* __restrict__ cumalog) {
  int bh = blockIdx.x;
  int b = bh >> 4, h = bh & 15, g = h >> 2;
  int tid = threadIdx.x;
  float hrun[16];
#pragma unroll
  for (int q = 0; q < 16; ++q) hrun[q] = 0.f;
  float* Hbase = hstate + (size_t)bh * 32 * 4096;
  for (int c = 0; c < 32; ++c) {
    float ca_last = cumalog[((size_t)b * kL + c * 64 + 63) * kG + g];
    float ca_prev = c ? cumalog[((size_t)b * kL + c * 64 - 1) * kG + g] : 0.f;
    float Dc = expf(ca_last - ca_prev);
    float* Hc = Hbase + (size_t)c * 4096;
#pragma unroll
    for (int q = 0; q < 16; ++q) {
      int idx = tid + q * 256;
      float local = Hc[idx];
      Hc[idx] = hrun[q];
      hrun[q] = Dc * hrun[q] + local;
    }
  }
}

// ---------------- K7: pass C — MFMA version
// LDS strides in elements (16B-aligned byte strides)
namespace {
constexpr int SC = 72;    // C/B tiles [128][72] bf16
constexpr int SG = 136;   // G/X/Wd/Ys [.][136] bf16
constexpr int SH = 72;    // h0t [64][72] bf16
constexpr int SW = 66;    // w table [64][66] f32
}
__global__ __launch_bounds__(256) void k_passC(const float* __restrict__ proj,
                                               const float* __restrict__ xmoe,
                                               const float* __restrict__ dtg,
                                               const float* __restrict__ cumalog,
                                               const float* __restrict__ hstate,
                                               const float* __restrict__ ydown,
                                               float* __restrict__ outY) {
  __shared__ __align__(16) char smem[162560];
  unsigned short* sCh = (unsigned short*)smem;              // [128][SC]
  unsigned short* sCl = sCh + 128 * SC;
  unsigned short* sBh = (unsigned short*)(smem + 36864);    // [128][SC]
  unsigned short* sBl = sBh + 128 * SC;
  float*          sW  = (float*)(smem + 73728);             // [64][SW]
  unsigned short* sHh = (unsigned short*)(smem + 73728);    // [64][SH] (reuse of sW)
  unsigned short* sHl = sHh + 64 * SH;
  unsigned short* sGh = (unsigned short*)(smem + 92160);    // [128][SG]
  unsigned short* sGl = sGh + 128 * SG;
  float* sca  = (float*)(smem + 161792);
  float* sdts = sca + 64;
  float* selx = sdts + 64;
  // phase-2 reuse
  unsigned short* sXh  = (unsigned short*)smem;             // [64][SG]
  unsigned short* sXl  = sXh + 64 * SG;
  unsigned short* sWdh = (unsigned short*)(smem + 36864);   // [64][SG]
  unsigned short* sWdl = sWdh + 64 * SG;
  unsigned short* sYh  = (unsigned short*)(smem + 92160);   // [64][SG]
  unsigned short* sYl  = sYh + 64 * SG;

  int bid = blockIdx.x;
  int c = bid & 31, h = (bid >> 5) & 15, b = bid >> 9, g = h >> 2;
  int tid = threadIdx.x;
  const int wave = tid >> 6, lane = tid & 63;
  const int fr = lane & 15, kq = lane >> 4;
  int base = c * 64;
  size_t tok0 = (size_t)b * kL + base;
  size_t projBase = tok0 * kDPROJ;

  // --- stage C, B (split), plus ca/dts/elx
  if (tid < 64) {
    float ca_prev = base ? cumalog[(tok0 - 1) * kG + g] : 0.f;
    float ca_t = cumalog[(tok0 + tid) * kG + g];
    sca[tid] = ca_t;
    sdts[tid] = dtg[(tok0 + tid) * kG + g];
    selx[tid] = exp2f((ca_t - ca_prev) * kLOG2E);
  }
  for (int m = tid; m < 8192; m += 256) {
    int s = m >> 7, j = m & 127;
    int row = s * 2 + (j & 1), col = j >> 1;
    unsigned short hh, ll;
    float cv = proj[projBase + (size_t)s * kDPROJ + COL_C + g * 128 + j];
    split2(cv, hh, ll);
    sCh[row * SC + col] = hh; sCl[row * SC + col] = ll;
    float bv = proj[projBase + (size_t)s * kDPROJ + COL_B + g * 128 + j];
    split2(bv, hh, ll);
    sBh[row * SC + col] = hh; sBl[row * SC + col] = ll;
  }
  __syncthreads();  // B1

  // --- w table + G = C · B^T   (G rows strip per wave: [wave*32, wave*32+32))
  for (int m = tid; m < 4096; m += 256) {
    int t = m >> 6, s = m & 63;
    float w = (s <= t) ? sdts[s] * exp2f((sca[t] - sca[s]) * kLOG2E) : 0.f;
    sW[t * SW + s] = w;
  }
  const int rowA0 = wave * 32;
  f32x4 gacc[2][8];
#pragma unroll
  for (int i = 0; i < 2; ++i)
#pragma unroll
    for (int j = 0; j < 8; ++j) gacc[i][j] = (f32x4){0.f, 0.f, 0.f, 0.f};
#pragma unroll
  for (int ks = 0; ks < 2; ++ks) {
    int kb = ks * 32 + kq * 8;
    bf16x8 ah[2], al[2];
#pragma unroll
    for (int mi = 0; mi < 2; ++mi) {
      int off = (rowA0 + mi * 16 + fr) * SC + kb;
      ah[mi] = ldsb8(sCh + off);
      al[mi] = ldsb8(sCl + off);
    }
#pragma unroll
    for (int ni = 0; ni < 8; ++ni) {
      int off = (ni * 16 + fr) * SC + kb;
      bf16x8 bh = ldsb8(sBh + off);
      bf16x8 bl = ldsb8(sBl + off);
#pragma unroll
      for (int mi = 0; mi < 2; ++mi) {
        gacc[mi][ni] = __builtin_amdgcn_mfma_f32_16x16x32_bf16(ah[mi], bh, gacc[mi][ni], 0, 0, 0);
        gacc[mi][ni] = __builtin_amdgcn_mfma_f32_16x16x32_bf16(ah[mi], bl, gacc[mi][ni], 0, 0, 0);
        gacc[mi][ni] = __builtin_amdgcn_mfma_f32_16x16x32_bf16(al[mi], bh, gacc[mi][ni], 0, 0, 0);
      }
    }
  }
  __syncthreads();  // B2 (w table complete)

  // --- mask + split-store G
#pragma unroll
  for (int mi = 0; mi < 2; ++mi)
#pragma unroll
    for (int ni = 0; ni < 8; ++ni) {
      int colg = ni * 16 + fr;
      int s = colg >> 1;
#pragma unroll
      for (int r = 0; r < 4; ++r) {
        int rowg = rowA0 + mi * 16 + kq * 4 + r;
        int t = rowg >> 1;
        float gm = gacc[mi][ni][r] * sW[t * SW + s];
        unsigned short hh, ll;
        split2(gm, hh, ll);
        sGh[rowg * SG + colg] = hh;
        sGl[rowg * SG + colg] = ll;
      }
    }
  __syncthreads();  // B3 (w fully consumed)

  // --- stage h0^T (into w region)
  for (int m = tid; m < 4096; m += 256) {
    int n = m >> 6, p = m & 63;
    float v = hstate[(size_t)bid * 4096 + m];
    unsigned short hh, ll;
    split2(v, hh, ll);
    sHh[p * SH + n] = hh;
    sHl[p * SH + n] = ll;
  }
  __syncthreads();  // B4

  // --- y0 = (C · h0^T) * elx[t]
  f32x4 yac[2][4];
#pragma unroll
  for (int i = 0; i < 2; ++i)
#pragma unroll
    for (int j = 0; j < 4; ++j) yac[i][j] = (f32x4){0.f, 0.f, 0.f, 0.f};
#pragma unroll
  for (int ks = 0; ks < 2; ++ks) {
    int kb = ks * 32 + kq * 8;
    bf16x8 ah[2], al[2];
#pragma unroll
    for (int mi = 0; mi < 2; ++mi) {
      int off = (rowA0 + mi * 16 + fr) * SC + kb;
      ah[mi] = ldsb8(sCh + off);
      al[mi] = ldsb8(sCl + off);
    }
#pragma unroll
    for (int ni = 0; ni < 4; ++ni) {
      int off = (ni * 16 + fr) * SH + kb;
      bf16x8 bh = ldsb8(sHh + off);
      bf16x8 bl = ldsb8(sHl + off);
#pragma unroll
      for (int mi = 0; mi < 2; ++mi) {
        yac[mi][ni] = __builtin_amdgcn_mfma_f32_16x16x32_bf16(ah[mi], bh, yac[mi][ni], 0, 0, 0);
        yac[mi][ni] = __builtin_amdgcn_mfma_f32_16x16x32_bf16(ah[mi], bl, yac[mi][ni], 0, 0, 0);
        yac[mi][ni] = __builtin_amdgcn_mfma_f32_16x16x32_bf16(al[mi], bh, yac[mi][ni], 0, 0, 0);
      }
    }
  }
#pragma unroll
  for (int mi = 0; mi < 2; ++mi)
#pragma unroll
    for (int r = 0; r < 4; ++r) {
      int t = (rowA0 + mi * 16 + kq * 4 + r) >> 1;
      float e = selx[t];
#pragma unroll
      for (int ni = 0; ni < 4; ++ni) yac[mi][ni][r] *= e;
    }
  __syncthreads();  // B5 (sC consumed)

  // --- stage X^T (over sC region) and Wd (over sB region)
  for (int m = tid; m < 8192; m += 256) {
    int s = m >> 7, j = m & 127;
    float xv = xmoe[((tok0 + s) * kH + h) * (size_t)128 + j];
    int p = j >> 1, cc = s * 2 + (j & 1);
    unsigned short hh, ll;
    split2(xv, hh, ll);
    sXh[p * SG + cc] = hh; sXl[p * SG + cc] = ll;
    float wv = ydown[m];
    split2(wv, hh, ll);
    sWdh[(m >> 7) * SG + (m & 127)] = hh;
    sWdl[(m >> 7) * SG + (m & 127)] = ll;
  }
  __syncthreads();  // B6

  // --- yac += G · X^T   (K = 128)
#pragma unroll
  for (int ks = 0; ks < 4; ++ks) {
    int kb = ks * 32 + kq * 8;
    bf16x8 ah[2], al[2];
#pragma unroll
    for (int mi = 0; mi < 2; ++mi) {
      int off = (rowA0 + mi * 16 + fr) * SG + kb;
      ah[mi] = ldsb8(sGh + off);
      al[mi] = ldsb8(sGl + off);
    }
#pragma unroll
    for (int ni = 0; ni < 4; ++ni) {
      int off = (ni * 16 + fr) * SG + kb;
      bf16x8 bh = ldsb8(sXh + off);
      bf16x8 bl = ldsb8(sXl + off);
#pragma unroll
      for (int mi = 0; mi < 2; ++mi) {
        yac[mi][ni] = __builtin_amdgcn_mfma_f32_16x16x32_bf16(ah[mi], bh, yac[mi][ni], 0, 0, 0);
        yac[mi][ni] = __builtin_amdgcn_mfma_f32_16x16x32_bf16(ah[mi], bl, yac[mi][ni], 0, 0, 0);
        yac[mi][ni] = __builtin_amdgcn_mfma_f32_16x16x32_bf16(al[mi], bh, yac[mi][ni], 0, 0, 0);
      }
    }
  }
  __syncthreads();  // B7 (sG consumed)

  // --- write Ys[t][p*2+r] (into sG region)
#pragma unroll
  for (int mi = 0; mi < 2; ++mi)
#pragma unroll
    for (int ni = 0; ni < 4; ++ni)
#pragma unroll
      for (int r = 0; r < 4; ++r) {
        int rowg = rowA0 + mi * 16 + kq * 4 + r;
        int t = rowg >> 1, rr = rowg & 1;
        int p = ni * 16 + fr;
        unsigned short hh, ll;
        split2(yac[mi][ni][r], hh, ll);
        sYh[t * SG + p * 2 + rr] = hh;
        sYl[t * SG + p * 2 + rr] = ll;
      }
  __syncthreads();  // B8

  // --- Z = Ys · Wd^T (64x64, K=128); wave strip rows [wave*16, wave*16+16)
  f32x4 zac[4];
#pragma unroll
  for (int j = 0; j < 4; ++j) zac[j] = (f32x4){0.f, 0.f, 0.f, 0.f};
#pragma unroll
  for (int ks = 0; ks < 4; ++ks) {
    int kb = ks * 32 + kq * 8;
    int offA = (wave * 16 + fr) * SG + kb;
    bf16x8 ah = ldsb8(sYh + offA);
    bf16x8 al = ldsb8(sYl + offA);
#pragma unroll
    for (int ni = 0; ni < 4; ++ni) {
      int off = (ni * 16 + fr) * SG + kb;
      bf16x8 bh = ldsb8(sWdh + off);
      bf16x8 bl = ldsb8(sWdl + off);
      zac[ni] = __builtin_amdgcn_mfma_f32_16x16x32_bf16(ah, bh, zac[ni], 0, 0, 0);
      zac[ni] = __builtin_amdgcn_mfma_f32_16x16x32_bf16(ah, bl, zac[ni], 0, 0, 0);
      zac[ni] = __builtin_amdgcn_mfma_f32_16x16x32_bf16(al, bh, zac[ni], 0, 0, 0);
    }
  }
#pragma unroll
  for (int ni = 0; ni < 4; ++ni)
#pragma unroll
    for (int r = 0; r < 4; ++r) {
      int t = wave * 16 + kq * 4 + r;
      int o = ni * 16 + fr;
      outY[(tok0 + t) * (size_t)1024 + h * 64 + o] = zac[ni][r];
    }
}

// ---------------- K8: gate
__global__ __launch_bounds__(256) void k_gate(float* __restrict__ y,
                                              const float* __restrict__ proj,
                                              const float* __restrict__ Dv,
                                              const float* __restrict__ pregate_w) {
  int tok = blockIdx.x;
  int tid = threadIdx.x;
  size_t yoff = (size_t)tok * 1024;
  size_t poff = (size_t)tok * kDPROJ;
  __shared__ float red[4];
  float vals[4];
  float ss = 0.f;
#pragma unroll
  for (int q = 0; q < 4; ++q) {
    int j = tid + q * 256;
    float v = y[yoff + j] + proj[poff + COL_XP + j] * Dv[j >> 6];
    vals[q] = v;
    ss += v * v;
  }
  for (int o = 1; o < 64; o <<= 1) ss += __shfl_xor(ss, o);
  if ((tid & 63) == 0) red[tid >> 6] = ss;
  __syncthreads();
  float tot = red[0] + red[1] + red[2] + red[3];
  float scale = rsqrtf(tot / 1024.f + 1e-5f);
#pragma unroll
  for (int q = 0; q < 4; ++q) {
    int j = tid + q * 256;
    float z = proj[poff + COL_Z + j];
    float sig = 1.f / (1.f + expf(-z));
    y[yoff + j] = vals[q] * scale * pregate_w[j] * sig;
  }
}

// ---------------- K9: oup Kron-MoE, in place on d_out
__global__ __launch_bounds__(256) void k_oup(float* __restrict__ y,
                                             const float* __restrict__ router,
                                             const float* __restrict__ Ae,
                                             const float* __restrict__ Be,
                                             const float* __restrict__ scale_,
                                             const float* __restrict__ bias_) {
  int tok = blockIdx.x;
  int tid = threadIdx.x;
  __shared__ float xs[1024];
  __shared__ float Ts[32][33];
  __shared__ float logits_s[64];
  __shared__ double partial[256];
  size_t yoff = (size_t)tok * 1024;
  for (int m = tid; m < 1024; m += 256) xs[m] = y[yoff + m];
  __syncthreads();
  {
    int e = tid & 63, q = tid >> 6;
    double acc = 0.0;
    const float* rw = router + (size_t)e * 1024 + q * 256;
    const float* xv = xs + q * 256;
    for (int d = 0; d < 256; ++d) acc += (double)rw[d] * (double)xv[d];
    partial[tid] = acc;
  }
  __syncthreads();
  if (tid < 64) {
    double l = partial[tid] + partial[tid + 64] + partial[tid + 128] + partial[tid + 192];
    logits_s[tid] = (float)l;
  }
  __syncthreads();
  float v1 = -INFINITY; int i1 = -1;
  for (int e = 0; e < 64; ++e) { float v = logits_s[e]; if (v > v1) { v1 = v; i1 = e; } }
  float v2 = -INFINITY; int i2 = -1;
  for (int e = 0; e < 64; ++e) { if (e == i1) continue; float v = logits_s[e]; if (v > v2) { v2 = v; i2 = e; } }
  float e12 = expf(v2 - v1);
  float p1 = 1.f / (1.f + e12), p2 = e12 / (1.f + e12);
  float out[4] = {0.f, 0.f, 0.f, 0.f};
  for (int kk = 0; kk < 2; ++kk) {
    int e = kk ? i2 : i1;
    float pw = kk ? p2 : p1;
    const float* A = Ae + (size_t)e * 1024;
    const float* Bm = Be + (size_t)e * 1024;
    __syncthreads();
    for (int m = tid; m < 1024; m += 256) {
      int i = m >> 5, p = m & 31;
      float t = 0.f;
#pragma unroll
      for (int j = 0; j < 32; ++j) t += xs[i * 32 + j] * Bm[p * 32 + j];
      Ts[i][p] = t;
    }
    __syncthreads();
#pragma unroll
    for (int q = 0; q < 4; ++q) {
      int cc = tid + q * 256;
      int o = cc >> 5, p = cc & 31;
      float a2 = 0.f;
#pragma unroll
      for (int i = 0; i < 32; ++i) a2 += A[o * 32 + i] * Ts[i][p];
      out[q] += pw * a2;
    }
  }
  float sc = scale_[0];
#pragma unroll
  for (int q = 0; q < 4; ++q) {
    int cc = tid + q * 256;
    y[yoff + cc] = out[q] * sc + bias_[cc];
  }
}

extern "C" void kernel_launch(void* const* d_in, const int* in_sizes, int n_in,
                              void* d_out, int out_size, void* d_ws, size_t ws_size,
                              hipStream_t stream) {
  const float* u          = (const float*)d_in[0];
  const float* in_proj_w  = (const float*)d_in[1];
  const float* in_proj_b  = (const float*)d_in[2];
  const float* xup_router = (const float*)d_in[3];
  const float* xup_A      = (const float*)d_in[4];
  const float* xup_B      = (const float*)d_in[5];
  const float* xup_scale  = (const float*)d_in[6];
  const float* xup_bias   = (const float*)d_in[7];
  const float* ydown_w    = (const float*)d_in[8];
  const float* oup_router = (const float*)d_in[9];
  const float* oup_A      = (const float*)d_in[10];
  const float* oup_B      = (const float*)d_in[11];
  const float* oup_scale  = (const float*)d_in[12];
  const float* oup_bias   = (const float*)d_in[13];
  const float* theta_log  = (const float*)d_in[14];
  const float* Dv         = (const float*)d_in[15];
  const float* normB_w    = (const float*)d_in[16];
  const float* normC_w    = (const float*)d_in[17];
  const float* bias_B     = (const float*)d_in[18];
  const float* bias_C     = (const float*)d_in[19];
  const float* pregate_w  = (const float*)d_in[20];

  char* ws = (char*)d_ws;
  float* proj = (float*)ws;      ws += (size_t)kTOK * kDPROJ * 4;
  float* dtg = (float*)ws;       ws += (size_t)kTOK * kG * 4;
  float* cumalog = (float*)ws;   ws += (size_t)kTOK * kG * 4;
  double* cumdt = (double*)ws;   ws += (size_t)kTOK * kG * 8;
  float* cs_tab = (float*)ws;    ws += (size_t)kTOK * kG * 32 * 2 * 4;
  float* xmoe = (float*)ws;      ws += (size_t)kTOK * kH * 128 * 4;
  float* hstate = (float*)ws;    ws += (size_t)kB * kH * kNC * 4096 * 4;
  float* outY = (float*)d_out;

  unsigned short* Uhi = (unsigned short*)xmoe;
  unsigned short* Ulo = Uhi + (size_t)kTOK * kDM;
  unsigned short* Whi = Ulo + (size_t)kTOK * kDM;
  unsigned short* Wlo = Whi + (size_t)kNPAD * kDM;

  k_split_u<<<dim3(kTOK * kDM / 4 / 256), dim3(256), 0, stream>>>(u, Uhi, Ulo);
  k_split_w<<<dim3(kNPAD * kDM / 4 / 256), dim3(256), 0, stream>>>(in_proj_w, Whi, Wlo);
  k_inproj_mfma<<<dim3(kTOK / 128, kNPAD / 128), dim3(256), 0, stream>>>(Uhi, Ulo, Whi, Wlo, in_proj_b, proj);
  k_dtprep<<<dim3(kB * kG), dim3(256), 0, stream>>>(proj, dtg, cumalog, cumdt);
  k_angles<<<dim3(kTOK * 128 / 256), dim3(256), 0, stream>>>(cumdt, theta_log, cs_tab);
  k_rotate<<<dim3(kTOK), dim3(256), 0, stream>>>(proj, cs_tab, normB_w, normC_w, bias_B, bias_C);
  k_xup<<<dim3(kTOK * kH / 4), dim3(256), 0, stream>>>(proj, xup_router, xup_A, xup_B, xup_scale, xup_bias, xmoe);
  k_passA<<<dim3(kB * kH * kNC), dim3(256), 0, stream>>>(proj, xmoe, dtg, cumalog, hstate);
  k_passB<<<dim3(kB * kH), dim3(256), 0, stream>>>(hstate, cumalog);
  k_passC<<<dim3(kB * kH * kNC), dim3(256), 0, stream>>>(proj, xmoe, dtg, cumalog, hstate, ydown_w, outY);
  k_gate<<<dim3(kTOK), dim3(256), 0, stream>>>(outY, proj, Dv, pregate_w);
  k_oup<<<dim3(kTOK), dim3(256), 0, stream>>>(outY, oup_router, oup_A, oup_B, oup_scale, oup_bias);
}

// Round 4
// 966.047 us; speedup vs baseline: 2.0698x; 1.0987x over previous
//
#include <hip/hip_runtime.h>
#include <hip/hip_bf16.h>
#include <math.h>

namespace {
constexpr int kB = 4, kL = 2048, kDM = 1024;
constexpr int kH = 16, kG = 4;
constexpr int kDPROJ = 3084;
constexpr int COL_Z = 0, COL_XP = 1024, COL_B = 2048, COL_C = 2560, COL_DT = 3072, COL_A = 3076;
constexpr int kTOK = kB * kL;           // 8192
constexpr int kNC = kL / 64;            // 32 chunks
constexpr int kNPAD = 3200;             // W padded rows (25 * 128)
constexpr float kLOG2E = 1.4426950408889634f;
}

typedef __attribute__((ext_vector_type(8))) __bf16 bf16x8;
typedef __attribute__((ext_vector_type(8))) unsigned short u16x8;
typedef __attribute__((ext_vector_type(4))) float f32x4;

#define GLDS16(gp, lp)                                                          \
  __builtin_amdgcn_global_load_lds(                                             \
      (const __attribute__((address_space(1))) void*)(gp),                      \
      (__attribute__((address_space(3))) void*)(lp), 16, 0, 0)

__device__ __forceinline__ unsigned short bf16_rne(float f) {
  unsigned u = __builtin_bit_cast(unsigned, f);
  unsigned r = u + 0x7fffu + ((u >> 16) & 1u);
  return (unsigned short)(r >> 16);
}
__device__ __forceinline__ void split2(float f, unsigned short& h, unsigned short& l) {
  unsigned short hh = bf16_rne(f);
  float hf = __builtin_bit_cast(float, (unsigned)hh << 16);
  h = hh;
  l = bf16_rne(f - hf);
}
__device__ __forceinline__ bf16x8 ldsb8(const unsigned short* p) {
  return __builtin_bit_cast(bf16x8, *(const u16x8*)p);
}

// ---------------- K0a: split U -> (hi, lo) bf16
__global__ __launch_bounds__(256) void k_split_u(const float* __restrict__ X,
                                                 unsigned short* __restrict__ hi,
                                                 unsigned short* __restrict__ lo) {
  int i = blockIdx.x * 256 + threadIdx.x;
  float4 x = ((const float4*)X)[i];
  float xs[4] = {x.x, x.y, x.z, x.w};
  ushort4 hv, lv;
  unsigned short hq[4], lq[4];
#pragma unroll
  for (int q = 0; q < 4; ++q) split2(xs[q], hq[q], lq[q]);
  hv.x = hq[0]; hv.y = hq[1]; hv.z = hq[2]; hv.w = hq[3];
  lv.x = lq[0]; lv.y = lq[1]; lv.z = lq[2]; lv.w = lq[3];
  ((ushort4*)hi)[i] = hv;
  ((ushort4*)lo)[i] = lv;
}

// ---------------- K0b: split W -> (hi, lo) bf16, padded to kNPAD rows
__global__ __launch_bounds__(256) void k_split_w(const float* __restrict__ X,
                                                 unsigned short* __restrict__ hi,
                                                 unsigned short* __restrict__ lo) {
  int i = blockIdx.x * 256 + threadIdx.x;
  int row = i >> 8;
  float4 x = make_float4(0.f, 0.f, 0.f, 0.f);
  if (row < kDPROJ) x = ((const float4*)X)[i];
  float xs[4] = {x.x, x.y, x.z, x.w};
  ushort4 hv, lv;
  unsigned short hq[4], lq[4];
#pragma unroll
  for (int q = 0; q < 4; ++q) split2(xs[q], hq[q], lq[q]);
  hv.x = hq[0]; hv.y = hq[1]; hv.z = hq[2]; hv.w = hq[3];
  lv.x = lq[0]; lv.y = lq[1]; lv.z = lq[2]; lv.w = lq[3];
  ((ushort4*)hi)[i] = hv;
  ((ushort4*)lo)[i] = lv;
}

// ---------------- K1: in_proj GEMM via split-bf16 MFMA
__global__ __launch_bounds__(256) void k_inproj_mfma(
    const unsigned short* __restrict__ Uhi, const unsigned short* __restrict__ Ulo,
    const unsigned short* __restrict__ Whi, const unsigned short* __restrict__ Wlo,
    const float* __restrict__ bias, float* __restrict__ proj) {
  __shared__ unsigned short lds_u[16384];
  const int tid = threadIdx.x;
  const int wave = tid >> 6, lane = tid & 63;
  const int wm = wave >> 1, wn = wave & 1;
  const int row0 = blockIdx.x * 128, col0 = blockIdx.y * 128;
  const int fr = lane & 15, kq = lane >> 4;

  f32x4 acc[4][4];
#pragma unroll
  for (int i = 0; i < 4; ++i)
#pragma unroll
    for (int j = 0; j < 4; ++j) acc[i][j] = (f32x4){0.f, 0.f, 0.f, 0.f};

  const int s0 = wave * 64 + lane;

  for (int k0 = 0; k0 < kDM; k0 += 32) {
#pragma unroll
    for (int q = 0; q < 2; ++q) {
      const int slot = q * 256 + s0;
      const int r = slot >> 2;
      const int ce = ((slot & 3) ^ ((r >> 1) & 3)) * 8;
      const size_t ao = (size_t)(row0 + r) * kDM + k0 + ce;
      const size_t bo = (size_t)(col0 + r) * kDM + k0 + ce;
      const int lb = (q * 256 + wave * 64) * 16;
      GLDS16(Uhi + ao, (char*)lds_u + lb);
      GLDS16(Ulo + ao, (char*)lds_u + 8192 + lb);
      GLDS16(Whi + bo, (char*)lds_u + 16384 + lb);
      GLDS16(Wlo + bo, (char*)lds_u + 24576 + lb);
    }
    __syncthreads();
    bf16x8 ahi[4], alo[4], bhi[4], blo[4];
#pragma unroll
    for (int mi = 0; mi < 4; ++mi) {
      int r = wm * 64 + mi * 16 + fr;
      int off = r * 32 + ((kq ^ ((r >> 1) & 3)) * 8);
      ahi[mi] = ldsb8(lds_u + off);
      alo[mi] = ldsb8(lds_u + 4096 + off);
    }
#pragma unroll
    for (int ni = 0; ni < 4; ++ni) {
      int r = wn * 64 + ni * 16 + fr;
      int off = r * 32 + ((kq ^ ((r >> 1) & 3)) * 8);
      bhi[ni] = ldsb8(lds_u + 8192 + off);
      blo[ni] = ldsb8(lds_u + 12288 + off);
    }
#pragma unroll
    for (int mi = 0; mi < 4; ++mi)
#pragma unroll
      for (int ni = 0; ni < 4; ++ni) {
        acc[mi][ni] = __builtin_amdgcn_mfma_f32_16x16x32_bf16(ahi[mi], bhi[ni], acc[mi][ni], 0, 0, 0);
        acc[mi][ni] = __builtin_amdgcn_mfma_f32_16x16x32_bf16(ahi[mi], blo[ni], acc[mi][ni], 0, 0, 0);
        acc[mi][ni] = __builtin_amdgcn_mfma_f32_16x16x32_bf16(alo[mi], bhi[ni], acc[mi][ni], 0, 0, 0);
      }
    __syncthreads();
  }

  const int orow = row0 + wm * 64, ocol = col0 + wn * 64;
#pragma unroll
  for (int mi = 0; mi < 4; ++mi)
#pragma unroll
    for (int ni = 0; ni < 4; ++ni) {
      int cg = ocol + ni * 16 + fr;
      if (cg < kDPROJ) {
        float bv = bias[cg];
#pragma unroll
        for (int r = 0; r < 4; ++r) {
          int rg = orow + mi * 16 + kq * 4 + r;
          proj[(size_t)rg * kDPROJ + cg] = acc[mi][ni][r] + bv;
        }
      }
    }
}

// ---------------- K2: dt prep + f64 scans
__global__ __launch_bounds__(256) void k_dtprep(const float* __restrict__ proj,
                                                float* __restrict__ dtg,
                                                float* __restrict__ cumalog,
                                                double* __restrict__ cumdt) {
  int bg = blockIdx.x;
  int b = bg / kG, g = bg % kG;
  int tid = threadIdx.x;
  __shared__ double s_dt[256], s_al[256];
  double loc_dt[8], loc_al[8];
  double sdt = 0.0, sal = 0.0;
#pragma unroll
  for (int q = 0; q < 8; ++q) {
    int t = tid * 8 + q;
    size_t i = (size_t)(b * kL + t) * kDPROJ;
    float rd = proj[i + COL_DT + g];
    float ra = proj[i + COL_A + g];
    float dt = rd > 20.f ? rd : log1pf(expf(rd));
    float al = -expf(ra) * dt;
    dtg[(size_t)(b * kL + t) * kG + g] = dt;
    sdt += (double)dt; loc_dt[q] = sdt;
    sal += (double)al; loc_al[q] = sal;
  }
  s_dt[tid] = sdt; s_al[tid] = sal;
  __syncthreads();
  for (int off = 1; off < 256; off <<= 1) {
    double a = 0.0, c = 0.0;
    if (tid >= off) { a = s_dt[tid - off]; c = s_al[tid - off]; }
    __syncthreads();
    s_dt[tid] += a; s_al[tid] += c;
    __syncthreads();
  }
  double base_dt = tid ? s_dt[tid - 1] : 0.0;
  double base_al = tid ? s_al[tid - 1] : 0.0;
#pragma unroll
  for (int q = 0; q < 8; ++q) {
    int t = tid * 8 + q;
    size_t idx = (size_t)(b * kL + t) * kG + g;
    cumdt[idx] = base_dt + loc_dt[q];
    cumalog[idx] = (float)(base_al + loc_al[q]);
  }
}

// ---------------- K2b: angle table
__global__ __launch_bounds__(256) void k_angles(const double* __restrict__ cumdt,
                                                const float* __restrict__ theta_log,
                                                float* __restrict__ cs_tab) {
  int idx = blockIdx.x * 256 + threadIdx.x;
  int tok = idx >> 7, gk = idx & 127, g = gk >> 5, k = gk & 31;
  double theta = exp((double)theta_log[g * 32 + k]);
  double ang = theta * cumdt[(size_t)tok * kG + g];
  const double twopi = 6.283185307179586476925286766559;
  double rem = ang - floor(ang / twopi) * twopi;
  cs_tab[(size_t)idx * 2] = cosf((float)rem);
  cs_tab[(size_t)idx * 2 + 1] = sinf((float)rem);
}

// ---------------- K3: RMS + bias + RoPE rotate of B/C, in place in proj
__global__ __launch_bounds__(256) void k_rotate(float* __restrict__ proj,
                                                const float* __restrict__ cs_tab,
                                                const float* __restrict__ normB_w,
                                                const float* __restrict__ normC_w,
                                                const float* __restrict__ bias_B,
                                                const float* __restrict__ bias_C) {
  int tok = blockIdx.x;
  int tid = threadIdx.x;
  __shared__ float buf[256];
  __shared__ float red[4];
  size_t rowoff = (size_t)tok * kDPROJ;
  int half = tid >> 7;
  int j = tid & 127;
  int wave = tid >> 6;
  for (int g = 0; g < kG; ++g) {
    int col = (half ? COL_C : COL_B) + g * 128 + j;
    float v = proj[rowoff + col];
    float ss = v * v;
    for (int o = 1; o < 64; o <<= 1) ss += __shfl_xor(ss, o);
    if ((tid & 63) == 0) red[wave] = ss;
    __syncthreads();
    float tot = red[half * 2] + red[half * 2 + 1];
    float scale = rsqrtf(tot / 128.f + 1e-5f);
    const float* nw = half ? normC_w : normB_w;
    const float* bb = half ? bias_C : bias_B;
    float nv = v * scale * nw[j] + bb[g * 128 + j];
    buf[tid] = nv;
    __syncthreads();
    float other = buf[tid ^ 2];
    int n = j >> 1, k = n >> 1;
    bool isRe = (n & 1) == 0;
    const float* cs = cs_tab + (((size_t)tok * kG + g) * 32 + k) * 2;
    float cc = cs[0], sn = cs[1];
    float out = isRe ? (nv * cc - other * sn) : (other * sn + nv * cc);
    proj[rowoff + col] = out;
    __syncthreads();
  }
}

// ---------------- K4: xup Kron-MoE -> xmoe (B,L,H,128)
__global__ __launch_bounds__(256) void k_xup(const float* __restrict__ proj,
                                             const float* __restrict__ router,
                                             const float* __restrict__ Ae,
                                             const float* __restrict__ Be,
                                             const float* __restrict__ scale_,
                                             const float* __restrict__ bias_,
                                             float* __restrict__ xmoe) {
  int wave = threadIdx.x >> 6, lane = threadIdx.x & 63;
  int unit = blockIdx.x * 4 + wave;
  int tok = unit >> 4, h = unit & 15;
  __shared__ float xs_all[4][64];
  __shared__ float Rs[64][65];
  for (int m = threadIdx.x; m < 64 * 64; m += 256) Rs[m >> 6][m & 63] = router[m];
  float xv = proj[(size_t)tok * kDPROJ + COL_XP + h * 64 + lane];
  xs_all[wave][lane] = xv;
  __syncthreads();
  const float* xs = xs_all[wave];
  double accd = 0.0;
#pragma unroll
  for (int d = 0; d < 64; ++d) accd += (double)Rs[lane][d] * (double)xs[d];
  float logit = (float)accd;
  float v1 = logit; int i1 = lane;
  for (int o = 1; o < 64; o <<= 1) {
    float vv = __shfl_xor(v1, o); int ii = __shfl_xor(i1, o);
    if (vv > v1 || (vv == v1 && ii < i1)) { v1 = vv; i1 = ii; }
  }
  float lm = (lane == i1) ? -INFINITY : logit;
  float v2 = lm; int i2 = lane;
  for (int o = 1; o < 64; o <<= 1) {
    float vv = __shfl_xor(v2, o); int ii = __shfl_xor(i2, o);
    if (vv > v2 || (vv == v2 && ii < i2)) { v2 = vv; i2 = ii; }
  }
  float e12 = expf(v2 - v1);
  float p1 = 1.f / (1.f + e12), p2 = e12 / (1.f + e12);
  float out0 = 0.f, out1 = 0.f;
#pragma unroll
  for (int kk = 0; kk < 2; ++kk) {
    int e = kk ? i2 : i1;
    float pw = kk ? p2 : p1;
    const float* A = Ae + (size_t)e * 64;
    const float* Bm = Be + (size_t)e * 128;
#pragma unroll
    for (int hlf = 0; hlf < 2; ++hlf) {
      int c = lane + hlf * 64;
      int o = c >> 4, p = c & 15;
      float y = 0.f;
#pragma unroll
      for (int i = 0; i < 8; ++i) {
        float t = 0.f;
#pragma unroll
        for (int jj = 0; jj < 8; ++jj) t += xs[i * 8 + jj] * Bm[p * 8 + jj];
        y += A[o * 8 + i] * t;
      }
      if (hlf) out1 += pw * y; else out0 += pw * y;
    }
  }
  float sc = scale_[0];
  size_t ob = (size_t)unit * 128;
  xmoe[ob + lane] = out0 * sc + bias_[lane];
  xmoe[ob + lane + 64] = out1 * sc + bias_[lane + 64];
}

// ---------------- K5: pass A — per-chunk local end state S_c
__global__ __launch_bounds__(256) void k_passA(const float* __restrict__ proj,
                                               const float* __restrict__ xmoe,
                                               const float* __restrict__ dtg,
                                               const float* __restrict__ cumalog,
                                               float* __restrict__ hstate) {
  int bid = blockIdx.x;
  int c = bid & 31, h = (bid >> 5) & 15, b = bid >> 9, g = h >> 2;
  int tid = threadIdx.x;
  __shared__ float Bs[128][65];
  __shared__ float Xs[128][65];
  __shared__ float wv[64];
  int base = c * 64;
  size_t tok0 = (size_t)b * kL + base;
  if (tid < 64) {
    float ca_last = cumalog[(tok0 + 63) * kG + g];
    float ca_s = cumalog[(tok0 + tid) * kG + g];
    float dt = dtg[(tok0 + tid) * kG + g];
    wv[tid] = expf(ca_last - ca_s) * dt;
  }
  __syncthreads();
  for (int m = tid; m < 8192; m += 256) {
    int s = m >> 7, j = m & 127;
    float bval = proj[(tok0 + s) * kDPROJ + COL_B + g * 128 + j];
    Bs[s * 2 + (j & 1)][j >> 1] = bval * wv[s];
    float xval = xmoe[((tok0 + s) * kH + h) * (size_t)128 + j];
    Xs[s * 2 + (j & 1)][j >> 1] = xval;
  }
  __syncthreads();
  int tx = tid & 15, ty = tid >> 4;
  float acc[4][4];
#pragma unroll
  for (int i = 0; i < 4; ++i)
#pragma unroll
    for (int j = 0; j < 4; ++j) acc[i][j] = 0.f;
  for (int k = 0; k < 128; ++k) {
    float a[4], bv[4];
#pragma unroll
    for (int q = 0; q < 4; ++q) a[q] = Bs[k][ty * 4 + q];
#pragma unroll
    for (int q = 0; q < 4; ++q) bv[q] = Xs[k][tx * 4 + q];
#pragma unroll
    for (int i = 0; i < 4; ++i)
#pragma unroll
      for (int j = 0; j < 4; ++j) acc[i][j] += a[i] * bv[j];
  }
  float* out = hstate + (size_t)bid * 4096;
#pragma unroll
  for (int i = 0; i < 4; ++i)
#pragma unroll
    for (int j = 0; j < 4; ++j)
      out[(ty * 4 + i) * 64 + tx * 4 + j] = acc[i][j];
}

// ---------------- K6: pass B — sequential inter-chunk combine
__global__ __launch_bounds__(256) void k_passB(float* __restrict__ hstate,
                                               const float* __restrict__ cumalog) {
  int bh = blockIdx.x;
  int b = bh >> 4, h = bh & 15, g = h >> 2;
  int tid = threadIdx.x;
  float hrun[16];
#pragma unroll
  for (int q = 0; q < 16; ++q) hrun[q] = 0.f;
  float* Hbase = hstate + (size_t)bh * 32 * 4096;
  for (int c = 0; c < 32; ++c) {
    float ca_last = cumalog[((size_t)b * kL + c * 64 + 63) * kG + g];
    float ca_prev = c ? cumalog[((size_t)b * kL + c * 64 - 1) * kG + g] : 0.f;
    float Dc = expf(ca_last - ca_prev);
    float* Hc = Hbase + (size_t)c * 4096;
#pragma unroll
    for (int q = 0; q < 16; ++q) {
      int idx = tid + q * 256;
      float local = Hc[idx];
      Hc[idx] = hrun[q];
      hrun[q] = Dc * hrun[q] + local;
    }
  }
}

// ---------------- K7: pass C — MFMA version
namespace {
constexpr int SC = 72;
constexpr int SG = 136;
constexpr int SH = 72;
constexpr int SW = 66;
}
__global__ __launch_bounds__(256) void k_passC(const float* __restrict__ proj,
                                               const float* __restrict__ xmoe,
                                               const float* __restrict__ dtg,
                                               const float* __restrict__ cumalog,
                                               const float* __restrict__ hstate,
                                               const float* __restrict__ ydown,
                                               float* __restrict__ outY) {
  __shared__ __align__(16) char smem[162560];
  unsigned short* sCh = (unsigned short*)smem;
  unsigned short* sCl = sCh + 128 * SC;
  unsigned short* sBh = (unsigned short*)(smem + 36864);
  unsigned short* sBl = sBh + 128 * SC;
  float*          sW  = (float*)(smem + 73728);
  unsigned short* sHh = (unsigned short*)(smem + 73728);
  unsigned short* sHl = sHh + 64 * SH;
  unsigned short* sGh = (unsigned short*)(smem + 92160);
  unsigned short* sGl = sGh + 128 * SG;
  float* sca  = (float*)(smem + 161792);
  float* sdts = sca + 64;
  float* selx = sdts + 64;
  unsigned short* sXh  = (unsigned short*)smem;
  unsigned short* sXl  = sXh + 64 * SG;
  unsigned short* sWdh = (unsigned short*)(smem + 36864);
  unsigned short* sWdl = sWdh + 64 * SG;
  unsigned short* sYh  = (unsigned short*)(smem + 92160);
  unsigned short* sYl  = sYh + 64 * SG;

  int bid = blockIdx.x;
  int c = bid & 31, h = (bid >> 5) & 15, b = bid >> 9, g = h >> 2;
  int tid = threadIdx.x;
  const int wave = tid >> 6, lane = tid & 63;
  const int fr = lane & 15, kq = lane >> 4;
  int base = c * 64;
  size_t tok0 = (size_t)b * kL + base;
  size_t projBase = tok0 * kDPROJ;

  if (tid < 64) {
    float ca_prev = base ? cumalog[(tok0 - 1) * kG + g] : 0.f;
    float ca_t = cumalog[(tok0 + tid) * kG + g];
    sca[tid] = ca_t;
    sdts[tid] = dtg[(tok0 + tid) * kG + g];
    selx[tid] = exp2f((ca_t - ca_prev) * kLOG2E);
  }
  for (int m = tid; m < 8192; m += 256) {
    int s = m >> 7, j = m & 127;
    int row = s * 2 + (j & 1), col = j >> 1;
    unsigned short hh, ll;
    float cv = proj[projBase + (size_t)s * kDPROJ + COL_C + g * 128 + j];
    split2(cv, hh, ll);
    sCh[row * SC + col] = hh; sCl[row * SC + col] = ll;
    float bv = proj[projBase + (size_t)s * kDPROJ + COL_B + g * 128 + j];
    split2(bv, hh, ll);
    sBh[row * SC + col] = hh; sBl[row * SC + col] = ll;
  }
  __syncthreads();  // B1

  for (int m = tid; m < 4096; m += 256) {
    int t = m >> 6, s = m & 63;
    float w = (s <= t) ? sdts[s] * exp2f((sca[t] - sca[s]) * kLOG2E) : 0.f;
    sW[t * SW + s] = w;
  }
  const int rowA0 = wave * 32;
  f32x4 gacc[2][8];
#pragma unroll
  for (int i = 0; i < 2; ++i)
#pragma unroll
    for (int j = 0; j < 8; ++j) gacc[i][j] = (f32x4){0.f, 0.f, 0.f, 0.f};
#pragma unroll
  for (int ks = 0; ks < 2; ++ks) {
    int kb = ks * 32 + kq * 8;
    bf16x8 ah[2], al[2];
#pragma unroll
    for (int mi = 0; mi < 2; ++mi) {
      int off = (rowA0 + mi * 16 + fr) * SC + kb;
      ah[mi] = ldsb8(sCh + off);
      al[mi] = ldsb8(sCl + off);
    }
#pragma unroll
    for (int ni = 0; ni < 8; ++ni) {
      int off = (ni * 16 + fr) * SC + kb;
      bf16x8 bh = ldsb8(sBh + off);
      bf16x8 bl = ldsb8(sBl + off);
#pragma unroll
      for (int mi = 0; mi < 2; ++mi) {
        gacc[mi][ni] = __builtin_amdgcn_mfma_f32_16x16x32_bf16(ah[mi], bh, gacc[mi][ni], 0, 0, 0);
        gacc[mi][ni] = __builtin_amdgcn_mfma_f32_16x16x32_bf16(ah[mi], bl, gacc[mi][ni], 0, 0, 0);
        gacc[mi][ni] = __builtin_amdgcn_mfma_f32_16x16x32_bf16(al[mi], bh, gacc[mi][ni], 0, 0, 0);
      }
    }
  }
  __syncthreads();  // B2

#pragma unroll
  for (int mi = 0; mi < 2; ++mi)
#pragma unroll
    for (int ni = 0; ni < 8; ++ni) {
      int colg = ni * 16 + fr;
      int s = colg >> 1;
#pragma unroll
      for (int r = 0; r < 4; ++r) {
        int rowg = rowA0 + mi * 16 + kq * 4 + r;
        int t = rowg >> 1;
        float gm = gacc[mi][ni][r] * sW[t * SW + s];
        unsigned short hh, ll;
        split2(gm, hh, ll);
        sGh[rowg * SG + colg] = hh;
        sGl[rowg * SG + colg] = ll;
      }
    }
  __syncthreads();  // B3

  for (int m = tid; m < 4096; m += 256) {
    int n = m >> 6, p = m & 63;
    float v = hstate[(size_t)bid * 4096 + m];
    unsigned short hh, ll;
    split2(v, hh, ll);
    sHh[p * SH + n] = hh;
    sHl[p * SH + n] = ll;
  }
  __syncthreads();  // B4

  f32x4 yac[2][4];
#pragma unroll
  for (int i = 0; i < 2; ++i)
#pragma unroll
    for (int j = 0; j < 4; ++j) yac[i][j] = (f32x4){0.f, 0.f, 0.f, 0.f};
#pragma unroll
  for (int ks = 0; ks < 2; ++ks) {
    int kb = ks * 32 + kq * 8;
    bf16x8 ah[2], al[2];
#pragma unroll
    for (int mi = 0; mi < 2; ++mi) {
      int off = (rowA0 + mi * 16 + fr) * SC + kb;
      ah[mi] = ldsb8(sCh + off);
      al[mi] = ldsb8(sCl + off);
    }
#pragma unroll
    for (int ni = 0; ni < 4; ++ni) {
      int off = (ni * 16 + fr) * SH + kb;
      bf16x8 bh = ldsb8(sHh + off);
      bf16x8 bl = ldsb8(sHl + off);
#pragma unroll
      for (int mi = 0; mi < 2; ++mi) {
        yac[mi][ni] = __builtin_amdgcn_mfma_f32_16x16x32_bf16(ah[mi], bh, yac[mi][ni], 0, 0, 0);
        yac[mi][ni] = __builtin_amdgcn_mfma_f32_16x16x32_bf16(ah[mi], bl, yac[mi][ni], 0, 0, 0);
        yac[mi][ni] = __builtin_amdgcn_mfma_f32_16x16x32_bf16(al[mi], bh, yac[mi][ni], 0, 0, 0);
      }
    }
  }
#pragma unroll
  for (int mi = 0; mi < 2; ++mi)
#pragma unroll
    for (int r = 0; r < 4; ++r) {
      int t = (rowA0 + mi * 16 + kq * 4 + r) >> 1;
      float e = selx[t];
#pragma unroll
      for (int ni = 0; ni < 4; ++ni) yac[mi][ni][r] *= e;
    }
  __syncthreads();  // B5

  for (int m = tid; m < 8192; m += 256) {
    int s = m >> 7, j = m & 127;
    float xv = xmoe[((tok0 + s) * kH + h) * (size_t)128 + j];
    int p = j >> 1, cc = s * 2 + (j & 1);
    unsigned short hh, ll;
    split2(xv, hh, ll);
    sXh[p * SG + cc] = hh; sXl[p * SG + cc] = ll;
    float wv = ydown[m];
    split2(wv, hh, ll);
    sWdh[(m >> 7) * SG + (m & 127)] = hh;
    sWdl[(m >> 7) * SG + (m & 127)] = ll;
  }
  __syncthreads();  // B6

#pragma unroll
  for (int ks = 0; ks < 4; ++ks) {
    int kb = ks * 32 + kq * 8;
    bf16x8 ah[2], al[2];
#pragma unroll
    for (int mi = 0; mi < 2; ++mi) {
      int off = (rowA0 + mi * 16 + fr) * SG + kb;
      ah[mi] = ldsb8(sGh + off);
      al[mi] = ldsb8(sGl + off);
    }
#pragma unroll
    for (int ni = 0; ni < 4; ++ni) {
      int off = (ni * 16 + fr) * SG + kb;
      bf16x8 bh = ldsb8(sXh + off);
      bf16x8 bl = ldsb8(sXl + off);
#pragma unroll
      for (int mi = 0; mi < 2; ++mi) {
        yac[mi][ni] = __builtin_amdgcn_mfma_f32_16x16x32_bf16(ah[mi], bh, yac[mi][ni], 0, 0, 0);
        yac[mi][ni] = __builtin_amdgcn_mfma_f32_16x16x32_bf16(ah[mi], bl, yac[mi][ni], 0, 0, 0);
        yac[mi][ni] = __builtin_amdgcn_mfma_f32_16x16x32_bf16(al[mi], bh, yac[mi][ni], 0, 0, 0);
      }
    }
  }
  __syncthreads();  // B7

#pragma unroll
  for (int mi = 0; mi < 2; ++mi)
#pragma unroll
    for (int ni = 0; ni < 4; ++ni)
#pragma unroll
      for (int r = 0; r < 4; ++r) {
        int rowg = rowA0 + mi * 16 + kq * 4 + r;
        int t = rowg >> 1, rr = rowg & 1;
        int p = ni * 16 + fr;
        unsigned short hh, ll;
        split2(yac[mi][ni][r], hh, ll);
        sYh[t * SG + p * 2 + rr] = hh;
        sYl[t * SG + p * 2 + rr] = ll;
      }
  __syncthreads();  // B8

  f32x4 zac[4];
#pragma unroll
  for (int j = 0; j < 4; ++j) zac[j] = (f32x4){0.f, 0.f, 0.f, 0.f};
#pragma unroll
  for (int ks = 0; ks < 4; ++ks) {
    int kb = ks * 32 + kq * 8;
    int offA = (wave * 16 + fr) * SG + kb;
    bf16x8 ah = ldsb8(sYh + offA);
    bf16x8 al = ldsb8(sYl + offA);
#pragma unroll
    for (int ni = 0; ni < 4; ++ni) {
      int off = (ni * 16 + fr) * SG + kb;
      bf16x8 bh = ldsb8(sWdh + off);
      bf16x8 bl = ldsb8(sWdl + off);
      zac[ni] = __builtin_amdgcn_mfma_f32_16x16x32_bf16(ah, bh, zac[ni], 0, 0, 0);
      zac[ni] = __builtin_amdgcn_mfma_f32_16x16x32_bf16(ah, bl, zac[ni], 0, 0, 0);
      zac[ni] = __builtin_amdgcn_mfma_f32_16x16x32_bf16(al, bh, zac[ni], 0, 0, 0);
    }
  }
#pragma unroll
  for (int ni = 0; ni < 4; ++ni)
#pragma unroll
    for (int r = 0; r < 4; ++r) {
      int t = wave * 16 + kq * 4 + r;
      int o = ni * 16 + fr;
      outY[(tok0 + t) * (size_t)1024 + h * 64 + o] = zac[ni][r];
    }
}

// ---------------- K8: gate
__global__ __launch_bounds__(256) void k_gate(float* __restrict__ y,
                                              const float* __restrict__ proj,
                                              const float* __restrict__ Dv,
                                              const float* __restrict__ pregate_w) {
  int tok = blockIdx.x;
  int tid = threadIdx.x;
  size_t yoff = (size_t)tok * 1024;
  size_t poff = (size_t)tok * kDPROJ;
  __shared__ float red[4];
  float vals[4];
  float ss = 0.f;
#pragma unroll
  for (int q = 0; q < 4; ++q) {
    int j = tid + q * 256;
    float v = y[yoff + j] + proj[poff + COL_XP + j] * Dv[j >> 6];
    vals[q] = v;
    ss += v * v;
  }
  for (int o = 1; o < 64; o <<= 1) ss += __shfl_xor(ss, o);
  if ((tid & 63) == 0) red[tid >> 6] = ss;
  __syncthreads();
  float tot = red[0] + red[1] + red[2] + red[3];
  float scale = rsqrtf(tot / 1024.f + 1e-5f);
#pragma unroll
  for (int q = 0; q < 4; ++q) {
    int j = tid + q * 256;
    float z = proj[poff + COL_Z + j];
    float sig = 1.f / (1.f + expf(-z));
    y[yoff + j] = vals[q] * scale * pregate_w[j] * sig;
  }
}

// ---------------- K8b: oup router logits — coalesced, LDS-tiled, f64 accum
// grid: kTOK/16 blocks; each block: 16 tokens x 64 experts
__global__ __launch_bounds__(256) void k_logits(const float* __restrict__ y,
                                                const float* __restrict__ router,
                                                float* __restrict__ logits) {
  __shared__ float Yt[16][65];
  __shared__ float Rt[64][65];
  int tid = threadIdx.x;
  int tok0 = blockIdx.x * 16;
  int t = tid & 15;          // token
  int e0 = (tid >> 4) * 4;   // 4 experts per thread
  double acc[4] = {0.0, 0.0, 0.0, 0.0};
  for (int kc = 0; kc < 1024; kc += 64) {
    for (int m = tid; m < 1024; m += 256) {
      int tt = m >> 6, c = m & 63;
      Yt[tt][c] = y[(size_t)(tok0 + tt) * 1024 + kc + c];
    }
    for (int m = tid; m < 4096; m += 256) {
      int ee = m >> 6, c = m & 63;
      Rt[ee][c] = router[(size_t)ee * 1024 + kc + c];
    }
    __syncthreads();
    for (int c = 0; c < 64; ++c) {
      float yv = Yt[t][c];
#pragma unroll
      for (int i = 0; i < 4; ++i)
        acc[i] += (double)Rt[e0 + i][c] * (double)yv;
    }
    __syncthreads();
  }
#pragma unroll
  for (int i = 0; i < 4; ++i)
    logits[(size_t)(tok0 + t) * 64 + e0 + i] = (float)acc[i];
}

// ---------------- K9: oup Kron-MoE, in place on d_out (logits precomputed)
__global__ __launch_bounds__(256) void k_oup(float* __restrict__ y,
                                             const float* __restrict__ logits,
                                             const float* __restrict__ Ae,
                                             const float* __restrict__ Be,
                                             const float* __restrict__ scale_,
                                             const float* __restrict__ bias_) {
  int tok = blockIdx.x;
  int tid = threadIdx.x;
  __shared__ float xs[1024];
  __shared__ float Ts[32][33];
  __shared__ float lg[64];
  size_t yoff = (size_t)tok * 1024;
  for (int m = tid; m < 1024; m += 256) xs[m] = y[yoff + m];
  if (tid < 64) lg[tid] = logits[(size_t)tok * 64 + tid];
  __syncthreads();
  float v1 = -INFINITY; int i1 = -1;
  for (int e = 0; e < 64; ++e) { float v = lg[e]; if (v > v1) { v1 = v; i1 = e; } }
  float v2 = -INFINITY; int i2 = -1;
  for (int e = 0; e < 64; ++e) { if (e == i1) continue; float v = lg[e]; if (v > v2) { v2 = v; i2 = e; } }
  float e12 = expf(v2 - v1);
  float p1 = 1.f / (1.f + e12), p2 = e12 / (1.f + e12);
  float out[4] = {0.f, 0.f, 0.f, 0.f};
  for (int kk = 0; kk < 2; ++kk) {
    int e = kk ? i2 : i1;
    float pw = kk ? p2 : p1;
    const float* A = Ae + (size_t)e * 1024;
    const float* Bm = Be + (size_t)e * 1024;
    __syncthreads();
    for (int m = tid; m < 1024; m += 256) {
      int i = m >> 5, p = m & 31;
      float t = 0.f;
#pragma unroll
      for (int j = 0; j < 32; ++j) t += xs[i * 32 + j] * Bm[p * 32 + j];
      Ts[i][p] = t;
    }
    __syncthreads();
#pragma unroll
    for (int q = 0; q < 4; ++q) {
      int cc = tid + q * 256;
      int o = cc >> 5, p = cc & 31;
      float a2 = 0.f;
#pragma unroll
      for (int i = 0; i < 32; ++i) a2 += A[o * 32 + i] * Ts[i][p];
      out[q] += pw * a2;
    }
  }
  float sc = scale_[0];
#pragma unroll
  for (int q = 0; q < 4; ++q) {
    int cc = tid + q * 256;
    y[yoff + cc] = out[q] * sc + bias_[cc];
  }
}

extern "C" void kernel_launch(void* const* d_in, const int* in_sizes, int n_in,
                              void* d_out, int out_size, void* d_ws, size_t ws_size,
                              hipStream_t stream) {
  const float* u          = (const float*)d_in[0];
  const float* in_proj_w  = (const float*)d_in[1];
  const float* in_proj_b  = (const float*)d_in[2];
  const float* xup_router = (const float*)d_in[3];
  const float* xup_A      = (const float*)d_in[4];
  const float* xup_B      = (const float*)d_in[5];
  const float* xup_scale  = (const float*)d_in[6];
  const float* xup_bias   = (const float*)d_in[7];
  const float* ydown_w    = (const float*)d_in[8];
  const float* oup_router = (const float*)d_in[9];
  const float* oup_A      = (const float*)d_in[10];
  const float* oup_B      = (const float*)d_in[11];
  const float* oup_scale  = (const float*)d_in[12];
  const float* oup_bias   = (const float*)d_in[13];
  const float* theta_log  = (const float*)d_in[14];
  const float* Dv         = (const float*)d_in[15];
  const float* normB_w    = (const float*)d_in[16];
  const float* normC_w    = (const float*)d_in[17];
  const float* bias_B     = (const float*)d_in[18];
  const float* bias_C     = (const float*)d_in[19];
  const float* pregate_w  = (const float*)d_in[20];

  char* ws = (char*)d_ws;
  float* proj = (float*)ws;      ws += (size_t)kTOK * kDPROJ * 4;
  float* dtg = (float*)ws;       ws += (size_t)kTOK * kG * 4;
  float* cumalog = (float*)ws;   ws += (size_t)kTOK * kG * 4;
  double* cumdt = (double*)ws;   ws += (size_t)kTOK * kG * 8;
  float* cs_tab = (float*)ws;    ws += (size_t)kTOK * kG * 32 * 2 * 4;
  float* xmoe = (float*)ws;      ws += (size_t)kTOK * kH * 128 * 4;
  float* hstate = (float*)ws;    ws += (size_t)kB * kH * kNC * 4096 * 4;
  float* outY = (float*)d_out;

  // logits alias the cs_tab region (dead after k_rotate)
  float* logits = cs_tab;        // kTOK * 64 * 4 = 2 MB << 8.39 MB

  unsigned short* Uhi = (unsigned short*)xmoe;
  unsigned short* Ulo = Uhi + (size_t)kTOK * kDM;
  unsigned short* Whi = Ulo + (size_t)kTOK * kDM;
  unsigned short* Wlo = Whi + (size_t)kNPAD * kDM;

  k_split_u<<<dim3(kTOK * kDM / 4 / 256), dim3(256), 0, stream>>>(u, Uhi, Ulo);
  k_split_w<<<dim3(kNPAD * kDM / 4 / 256), dim3(256), 0, stream>>>(in_proj_w, Whi, Wlo);
  k_inproj_mfma<<<dim3(kTOK / 128, kNPAD / 128), dim3(256), 0, stream>>>(Uhi, Ulo, Whi, Wlo, in_proj_b, proj);
  k_dtprep<<<dim3(kB * kG), dim3(256), 0, stream>>>(proj, dtg, cumalog, cumdt);
  k_angles<<<dim3(kTOK * 128 / 256), dim3(256), 0, stream>>>(cumdt, theta_log, cs_tab);
  k_rotate<<<dim3(kTOK), dim3(256), 0, stream>>>(proj, cs_tab, normB_w, normC_w, bias_B, bias_C);
  k_xup<<<dim3(kTOK * kH / 4), dim3(256), 0, stream>>>(proj, xup_router, xup_A, xup_B, xup_scale, xup_bias, xmoe);
  k_passA<<<dim3(kB * kH * kNC), dim3(256), 0, stream>>>(proj, xmoe, dtg, cumalog, hstate);
  k_passB<<<dim3(kB * kH), dim3(256), 0, stream>>>(hstate, cumalog);
  k_passC<<<dim3(kB * kH * kNC), dim3(256), 0, stream>>>(proj, xmoe, dtg, cumalog, hstate, ydown_w, outY);
  k_gate<<<dim3(kTOK), dim3(256), 0, stream>>>(outY, proj, Dv, pregate_w);
  k_logits<<<dim3(kTOK / 16), dim3(256), 0, stream>>>(outY, oup_router, logits);
  k_oup<<<dim3(kTOK), dim3(256), 0, stream>>>(outY, logits, oup_A, oup_B, oup_scale, oup_bias);
}

// Round 5
// 856.514 us; speedup vs baseline: 2.3345x; 1.1279x over previous
//
#include <hip/hip_runtime.h>
#include <hip/hip_bf16.h>
#include <math.h>

namespace {
constexpr int kB = 4, kL = 2048, kDM = 1024;
constexpr int kH = 16, kG = 4;
constexpr int kDPROJ = 3084;
constexpr int COL_Z = 0, COL_XP = 1024, COL_B = 2048, COL_C = 2560, COL_DT = 3072, COL_A = 3076;
constexpr int kTOK = kB * kL;           // 8192
constexpr int kNC = kL / 64;            // 32 chunks
constexpr int kNPAD = 3200;             // W padded rows (25 * 128)
constexpr float kLOG2E = 1.4426950408889634f;
}

typedef __attribute__((ext_vector_type(8))) __bf16 bf16x8;
typedef __attribute__((ext_vector_type(8))) unsigned short u16x8;
typedef __attribute__((ext_vector_type(4))) float f32x4;

#define GLDS16(gp, lp)                                                          \
  __builtin_amdgcn_global_load_lds(                                             \
      (const __attribute__((address_space(1))) void*)(gp),                      \
      (__attribute__((address_space(3))) void*)(lp), 16, 0, 0)

__device__ __forceinline__ unsigned short bf16_rne(float f) {
  unsigned u = __builtin_bit_cast(unsigned, f);
  unsigned r = u + 0x7fffu + ((u >> 16) & 1u);
  return (unsigned short)(r >> 16);
}
__device__ __forceinline__ void split2(float f, unsigned short& h, unsigned short& l) {
  unsigned short hh = bf16_rne(f);
  float hf = __builtin_bit_cast(float, (unsigned)hh << 16);
  h = hh;
  l = bf16_rne(f - hf);
}
__device__ __forceinline__ bf16x8 ldsb8(const unsigned short* p) {
  return __builtin_bit_cast(bf16x8, *(const u16x8*)p);
}

// ---------------- K0a: split U -> (hi, lo) bf16
__global__ __launch_bounds__(256) void k_split_u(const float* __restrict__ X,
                                                 unsigned short* __restrict__ hi,
                                                 unsigned short* __restrict__ lo) {
  int i = blockIdx.x * 256 + threadIdx.x;
  float4 x = ((const float4*)X)[i];
  float xs[4] = {x.x, x.y, x.z, x.w};
  ushort4 hv, lv;
  unsigned short hq[4], lq[4];
#pragma unroll
  for (int q = 0; q < 4; ++q) split2(xs[q], hq[q], lq[q]);
  hv.x = hq[0]; hv.y = hq[1]; hv.z = hq[2]; hv.w = hq[3];
  lv.x = lq[0]; lv.y = lq[1]; lv.z = lq[2]; lv.w = lq[3];
  ((ushort4*)hi)[i] = hv;
  ((ushort4*)lo)[i] = lv;
}

// ---------------- K0b: split W -> (hi, lo) bf16, padded to kNPAD rows
__global__ __launch_bounds__(256) void k_split_w(const float* __restrict__ X,
                                                 unsigned short* __restrict__ hi,
                                                 unsigned short* __restrict__ lo) {
  int i = blockIdx.x * 256 + threadIdx.x;
  int row = i >> 8;
  float4 x = make_float4(0.f, 0.f, 0.f, 0.f);
  if (row < kDPROJ) x = ((const float4*)X)[i];
  float xs[4] = {x.x, x.y, x.z, x.w};
  ushort4 hv, lv;
  unsigned short hq[4], lq[4];
#pragma unroll
  for (int q = 0; q < 4; ++q) split2(xs[q], hq[q], lq[q]);
  hv.x = hq[0]; hv.y = hq[1]; hv.z = hq[2]; hv.w = hq[3];
  lv.x = lq[0]; lv.y = lq[1]; lv.z = lq[2]; lv.w = lq[3];
  ((ushort4*)hi)[i] = hv;
  ((ushort4*)lo)[i] = lv;
}

// ---------------- K1: in_proj GEMM via split-bf16 MFMA
__global__ __launch_bounds__(256) void k_inproj_mfma(
    const unsigned short* __restrict__ Uhi, const unsigned short* __restrict__ Ulo,
    const unsigned short* __restrict__ Whi, const unsigned short* __restrict__ Wlo,
    const float* __restrict__ bias, float* __restrict__ proj) {
  __shared__ unsigned short lds_u[16384];
  const int tid = threadIdx.x;
  const int wave = tid >> 6, lane = tid & 63;
  const int wm = wave >> 1, wn = wave & 1;
  const int row0 = blockIdx.x * 128, col0 = blockIdx.y * 128;
  const int fr = lane & 15, kq = lane >> 4;

  f32x4 acc[4][4];
#pragma unroll
  for (int i = 0; i < 4; ++i)
#pragma unroll
    for (int j = 0; j < 4; ++j) acc[i][j] = (f32x4){0.f, 0.f, 0.f, 0.f};

  const int s0 = wave * 64 + lane;

  for (int k0 = 0; k0 < kDM; k0 += 32) {
#pragma unroll
    for (int q = 0; q < 2; ++q) {
      const int slot = q * 256 + s0;
      const int r = slot >> 2;
      const int ce = ((slot & 3) ^ ((r >> 1) & 3)) * 8;
      const size_t ao = (size_t)(row0 + r) * kDM + k0 + ce;
      const size_t bo = (size_t)(col0 + r) * kDM + k0 + ce;
      const int lb = (q * 256 + wave * 64) * 16;
      GLDS16(Uhi + ao, (char*)lds_u + lb);
      GLDS16(Ulo + ao, (char*)lds_u + 8192 + lb);
      GLDS16(Whi + bo, (char*)lds_u + 16384 + lb);
      GLDS16(Wlo + bo, (char*)lds_u + 24576 + lb);
    }
    __syncthreads();
    bf16x8 ahi[4], alo[4], bhi[4], blo[4];
#pragma unroll
    for (int mi = 0; mi < 4; ++mi) {
      int r = wm * 64 + mi * 16 + fr;
      int off = r * 32 + ((kq ^ ((r >> 1) & 3)) * 8);
      ahi[mi] = ldsb8(lds_u + off);
      alo[mi] = ldsb8(lds_u + 4096 + off);
    }
#pragma unroll
    for (int ni = 0; ni < 4; ++ni) {
      int r = wn * 64 + ni * 16 + fr;
      int off = r * 32 + ((kq ^ ((r >> 1) & 3)) * 8);
      bhi[ni] = ldsb8(lds_u + 8192 + off);
      blo[ni] = ldsb8(lds_u + 12288 + off);
    }
#pragma unroll
    for (int mi = 0; mi < 4; ++mi)
#pragma unroll
      for (int ni = 0; ni < 4; ++ni) {
        acc[mi][ni] = __builtin_amdgcn_mfma_f32_16x16x32_bf16(ahi[mi], bhi[ni], acc[mi][ni], 0, 0, 0);
        acc[mi][ni] = __builtin_amdgcn_mfma_f32_16x16x32_bf16(ahi[mi], blo[ni], acc[mi][ni], 0, 0, 0);
        acc[mi][ni] = __builtin_amdgcn_mfma_f32_16x16x32_bf16(alo[mi], bhi[ni], acc[mi][ni], 0, 0, 0);
      }
    __syncthreads();
  }

  const int orow = row0 + wm * 64, ocol = col0 + wn * 64;
#pragma unroll
  for (int mi = 0; mi < 4; ++mi)
#pragma unroll
    for (int ni = 0; ni < 4; ++ni) {
      int cg = ocol + ni * 16 + fr;
      if (cg < kDPROJ) {
        float bv = bias[cg];
#pragma unroll
        for (int r = 0; r < 4; ++r) {
          int rg = orow + mi * 16 + kq * 4 + r;
          proj[(size_t)rg * kDPROJ + cg] = acc[mi][ni][r] + bv;
        }
      }
    }
}

// ---------------- K2: dt prep + f64 scans
__global__ __launch_bounds__(256) void k_dtprep(const float* __restrict__ proj,
                                                float* __restrict__ dtg,
                                                float* __restrict__ cumalog,
                                                double* __restrict__ cumdt) {
  int bg = blockIdx.x;
  int b = bg / kG, g = bg % kG;
  int tid = threadIdx.x;
  __shared__ double s_dt[256], s_al[256];
  double loc_dt[8], loc_al[8];
  double sdt = 0.0, sal = 0.0;
#pragma unroll
  for (int q = 0; q < 8; ++q) {
    int t = tid * 8 + q;
    size_t i = (size_t)(b * kL + t) * kDPROJ;
    float rd = proj[i + COL_DT + g];
    float ra = proj[i + COL_A + g];
    float dt = rd > 20.f ? rd : log1pf(expf(rd));
    float al = -expf(ra) * dt;
    dtg[(size_t)(b * kL + t) * kG + g] = dt;
    sdt += (double)dt; loc_dt[q] = sdt;
    sal += (double)al; loc_al[q] = sal;
  }
  s_dt[tid] = sdt; s_al[tid] = sal;
  __syncthreads();
  for (int off = 1; off < 256; off <<= 1) {
    double a = 0.0, c = 0.0;
    if (tid >= off) { a = s_dt[tid - off]; c = s_al[tid - off]; }
    __syncthreads();
    s_dt[tid] += a; s_al[tid] += c;
    __syncthreads();
  }
  double base_dt = tid ? s_dt[tid - 1] : 0.0;
  double base_al = tid ? s_al[tid - 1] : 0.0;
#pragma unroll
  for (int q = 0; q < 8; ++q) {
    int t = tid * 8 + q;
    size_t idx = (size_t)(b * kL + t) * kG + g;
    cumdt[idx] = base_dt + loc_dt[q];
    cumalog[idx] = (float)(base_al + loc_al[q]);
  }
}

// ---------------- K2b: angle table
__global__ __launch_bounds__(256) void k_angles(const double* __restrict__ cumdt,
                                                const float* __restrict__ theta_log,
                                                float* __restrict__ cs_tab) {
  int idx = blockIdx.x * 256 + threadIdx.x;
  int tok = idx >> 7, gk = idx & 127, g = gk >> 5, k = gk & 31;
  double theta = exp((double)theta_log[g * 32 + k]);
  double ang = theta * cumdt[(size_t)tok * kG + g];
  const double twopi = 6.283185307179586476925286766559;
  double rem = ang - floor(ang / twopi) * twopi;
  cs_tab[(size_t)idx * 2] = cosf((float)rem);
  cs_tab[(size_t)idx * 2 + 1] = sinf((float)rem);
}

// ---------------- K3: RMS + bias + RoPE rotate of B/C, in place in proj
__global__ __launch_bounds__(256) void k_rotate(float* __restrict__ proj,
                                                const float* __restrict__ cs_tab,
                                                const float* __restrict__ normB_w,
                                                const float* __restrict__ normC_w,
                                                const float* __restrict__ bias_B,
                                                const float* __restrict__ bias_C) {
  int tok = blockIdx.x;
  int tid = threadIdx.x;
  __shared__ float buf[256];
  __shared__ float red[4];
  size_t rowoff = (size_t)tok * kDPROJ;
  int half = tid >> 7;
  int j = tid & 127;
  int wave = tid >> 6;
  for (int g = 0; g < kG; ++g) {
    int col = (half ? COL_C : COL_B) + g * 128 + j;
    float v = proj[rowoff + col];
    float ss = v * v;
    for (int o = 1; o < 64; o <<= 1) ss += __shfl_xor(ss, o);
    if ((tid & 63) == 0) red[wave] = ss;
    __syncthreads();
    float tot = red[half * 2] + red[half * 2 + 1];
    float scale = rsqrtf(tot / 128.f + 1e-5f);
    const float* nw = half ? normC_w : normB_w;
    const float* bb = half ? bias_C : bias_B;
    float nv = v * scale * nw[j] + bb[g * 128 + j];
    buf[tid] = nv;
    __syncthreads();
    float other = buf[tid ^ 2];
    int n = j >> 1, k = n >> 1;
    bool isRe = (n & 1) == 0;
    const float* cs = cs_tab + (((size_t)tok * kG + g) * 32 + k) * 2;
    float cc = cs[0], sn = cs[1];
    float out = isRe ? (nv * cc - other * sn) : (other * sn + nv * cc);
    proj[rowoff + col] = out;
    __syncthreads();
  }
}

// ---------------- K4: xup Kron-MoE -> xmoe (B,L,H,128)
__global__ __launch_bounds__(256) void k_xup(const float* __restrict__ proj,
                                             const float* __restrict__ router,
                                             const float* __restrict__ Ae,
                                             const float* __restrict__ Be,
                                             const float* __restrict__ scale_,
                                             const float* __restrict__ bias_,
                                             float* __restrict__ xmoe) {
  int wave = threadIdx.x >> 6, lane = threadIdx.x & 63;
  int unit = blockIdx.x * 4 + wave;
  int tok = unit >> 4, h = unit & 15;
  __shared__ float xs_all[4][64];
  __shared__ float Rs[64][65];
  for (int m = threadIdx.x; m < 64 * 64; m += 256) Rs[m >> 6][m & 63] = router[m];
  float xv = proj[(size_t)tok * kDPROJ + COL_XP + h * 64 + lane];
  xs_all[wave][lane] = xv;
  __syncthreads();
  const float* xs = xs_all[wave];
  double accd = 0.0;
#pragma unroll
  for (int d = 0; d < 64; ++d) accd += (double)Rs[lane][d] * (double)xs[d];
  float logit = (float)accd;
  float v1 = logit; int i1 = lane;
  for (int o = 1; o < 64; o <<= 1) {
    float vv = __shfl_xor(v1, o); int ii = __shfl_xor(i1, o);
    if (vv > v1 || (vv == v1 && ii < i1)) { v1 = vv; i1 = ii; }
  }
  float lm = (lane == i1) ? -INFINITY : logit;
  float v2 = lm; int i2 = lane;
  for (int o = 1; o < 64; o <<= 1) {
    float vv = __shfl_xor(v2, o); int ii = __shfl_xor(i2, o);
    if (vv > v2 || (vv == v2 && ii < i2)) { v2 = vv; i2 = ii; }
  }
  float e12 = expf(v2 - v1);
  float p1 = 1.f / (1.f + e12), p2 = e12 / (1.f + e12);
  float out0 = 0.f, out1 = 0.f;
#pragma unroll
  for (int kk = 0; kk < 2; ++kk) {
    int e = kk ? i2 : i1;
    float pw = kk ? p2 : p1;
    const float* A = Ae + (size_t)e * 64;
    const float* Bm = Be + (size_t)e * 128;
#pragma unroll
    for (int hlf = 0; hlf < 2; ++hlf) {
      int c = lane + hlf * 64;
      int o = c >> 4, p = c & 15;
      float y = 0.f;
#pragma unroll
      for (int i = 0; i < 8; ++i) {
        float t = 0.f;
#pragma unroll
        for (int jj = 0; jj < 8; ++jj) t += xs[i * 8 + jj] * Bm[p * 8 + jj];
        y += A[o * 8 + i] * t;
      }
      if (hlf) out1 += pw * y; else out0 += pw * y;
    }
  }
  float sc = scale_[0];
  size_t ob = (size_t)unit * 128;
  xmoe[ob + lane] = out0 * sc + bias_[lane];
  xmoe[ob + lane + 64] = out1 * sc + bias_[lane + 64];
}

// ---------------- K5: pass A — per-chunk local end state S_c
__global__ __launch_bounds__(256) void k_passA(const float* __restrict__ proj,
                                               const float* __restrict__ xmoe,
                                               const float* __restrict__ dtg,
                                               const float* __restrict__ cumalog,
                                               float* __restrict__ hstate) {
  int bid = blockIdx.x;
  int c = bid & 31, h = (bid >> 5) & 15, b = bid >> 9, g = h >> 2;
  int tid = threadIdx.x;
  __shared__ float Bs[128][65];
  __shared__ float Xs[128][65];
  __shared__ float wv[64];
  int base = c * 64;
  size_t tok0 = (size_t)b * kL + base;
  if (tid < 64) {
    float ca_last = cumalog[(tok0 + 63) * kG + g];
    float ca_s = cumalog[(tok0 + tid) * kG + g];
    float dt = dtg[(tok0 + tid) * kG + g];
    wv[tid] = expf(ca_last - ca_s) * dt;
  }
  __syncthreads();
  for (int m = tid; m < 8192; m += 256) {
    int s = m >> 7, j = m & 127;
    float bval = proj[(tok0 + s) * kDPROJ + COL_B + g * 128 + j];
    Bs[s * 2 + (j & 1)][j >> 1] = bval * wv[s];
    float xval = xmoe[((tok0 + s) * kH + h) * (size_t)128 + j];
    Xs[s * 2 + (j & 1)][j >> 1] = xval;
  }
  __syncthreads();
  int tx = tid & 15, ty = tid >> 4;
  float acc[4][4];
#pragma unroll
  for (int i = 0; i < 4; ++i)
#pragma unroll
    for (int j = 0; j < 4; ++j) acc[i][j] = 0.f;
  for (int k = 0; k < 128; ++k) {
    float a[4], bv[4];
#pragma unroll
    for (int q = 0; q < 4; ++q) a[q] = Bs[k][ty * 4 + q];
#pragma unroll
    for (int q = 0; q < 4; ++q) bv[q] = Xs[k][tx * 4 + q];
#pragma unroll
    for (int i = 0; i < 4; ++i)
#pragma unroll
      for (int j = 0; j < 4; ++j) acc[i][j] += a[i] * bv[j];
  }
  float* out = hstate + (size_t)bid * 4096;
#pragma unroll
  for (int i = 0; i < 4; ++i)
#pragma unroll
    for (int j = 0; j < 4; ++j)
      out[(ty * 4 + i) * 64 + tx * 4 + j] = acc[i][j];
}

// ---------------- K6: pass B — sequential inter-chunk combine
__global__ __launch_bounds__(256) void k_passB(float* __restrict__ hstate,
                                               const float* __restrict__ cumalog) {
  int bh = blockIdx.x;
  int b = bh >> 4, h = bh & 15, g = h >> 2;
  int tid = threadIdx.x;
  float hrun[16];
#pragma unroll
  for (int q = 0; q < 16; ++q) hrun[q] = 0.f;
  float* Hbase = hstate + (size_t)bh * 32 * 4096;
  for (int c = 0; c < 32; ++c) {
    float ca_last = cumalog[((size_t)b * kL + c * 64 + 63) * kG + g];
    float ca_prev = c ? cumalog[((size_t)b * kL + c * 64 - 1) * kG + g] : 0.f;
    float Dc = expf(ca_last - ca_prev);
    float* Hc = Hbase + (size_t)c * 4096;
#pragma unroll
    for (int q = 0; q < 16; ++q) {
      int idx = tid + q * 256;
      float local = Hc[idx];
      Hc[idx] = hrun[q];
      hrun[q] = Dc * hrun[q] + local;
    }
  }
}

// ---------------- K7: pass C — MFMA, 1024 threads (16 waves) for latency hiding
namespace {
constexpr int SC = 72;
constexpr int SG = 136;
constexpr int SH = 72;
constexpr int SW = 66;
}
__global__ __launch_bounds__(1024) void k_passC(const float* __restrict__ proj,
                                                const float* __restrict__ xmoe,
                                                const float* __restrict__ dtg,
                                                const float* __restrict__ cumalog,
                                                const float* __restrict__ hstate,
                                                const float* __restrict__ ydown,
                                                float* __restrict__ outY) {
  __shared__ __align__(16) char smem[162560];
  unsigned short* sCh = (unsigned short*)smem;
  unsigned short* sCl = sCh + 128 * SC;
  unsigned short* sBh = (unsigned short*)(smem + 36864);
  unsigned short* sBl = sBh + 128 * SC;
  float*          sW  = (float*)(smem + 73728);
  unsigned short* sHh = (unsigned short*)(smem + 73728);
  unsigned short* sHl = sHh + 64 * SH;
  unsigned short* sGh = (unsigned short*)(smem + 92160);
  unsigned short* sGl = sGh + 128 * SG;
  float* sca  = (float*)(smem + 161792);
  float* sdts = sca + 64;
  float* selx = sdts + 64;
  unsigned short* sXh  = (unsigned short*)smem;
  unsigned short* sXl  = sXh + 64 * SG;
  unsigned short* sWdh = (unsigned short*)(smem + 36864);
  unsigned short* sWdl = sWdh + 64 * SG;
  unsigned short* sYh  = (unsigned short*)(smem + 92160);
  unsigned short* sYl  = sYh + 64 * SG;

  int bid = blockIdx.x;
  int c = bid & 31, h = (bid >> 5) & 15, b = bid >> 9, g = h >> 2;
  int tid = threadIdx.x;
  const int wave = tid >> 6, lane = tid & 63;
  const int fr = lane & 15, kq = lane >> 4;
  int base = c * 64;
  size_t tok0 = (size_t)b * kL + base;
  size_t projBase = tok0 * kDPROJ;

  if (tid < 64) {
    float ca_prev = base ? cumalog[(tok0 - 1) * kG + g] : 0.f;
    float ca_t = cumalog[(tok0 + tid) * kG + g];
    sca[tid] = ca_t;
    sdts[tid] = dtg[(tok0 + tid) * kG + g];
    selx[tid] = exp2f((ca_t - ca_prev) * kLOG2E);
  }
  for (int m = tid; m < 8192; m += 1024) {
    int s = m >> 7, j = m & 127;
    int row = s * 2 + (j & 1), col = j >> 1;
    unsigned short hh, ll;
    float cv = proj[projBase + (size_t)s * kDPROJ + COL_C + g * 128 + j];
    split2(cv, hh, ll);
    sCh[row * SC + col] = hh; sCl[row * SC + col] = ll;
    float bv = proj[projBase + (size_t)s * kDPROJ + COL_B + g * 128 + j];
    split2(bv, hh, ll);
    sBh[row * SC + col] = hh; sBl[row * SC + col] = ll;
  }
  __syncthreads();  // B1

  // w table
  for (int m = tid; m < 4096; m += 1024) {
    int t = m >> 6, s = m & 63;
    float w = (s <= t) ? sdts[s] * exp2f((sca[t] - sca[s]) * kLOG2E) : 0.f;
    sW[t * SW + s] = w;
  }
  // G = C · B^T : wave (r8 = wave&7) rows r8*16, col half (wave>>3)*64
  const int rowA0 = (wave & 7) * 16;
  const int colH = wave >> 3;
  f32x4 gacc[4];
#pragma unroll
  for (int j = 0; j < 4; ++j) gacc[j] = (f32x4){0.f, 0.f, 0.f, 0.f};
#pragma unroll
  for (int ks = 0; ks < 2; ++ks) {
    int kb = ks * 32 + kq * 8;
    int offA = (rowA0 + fr) * SC + kb;
    bf16x8 ah = ldsb8(sCh + offA);
    bf16x8 al = ldsb8(sCl + offA);
#pragma unroll
    for (int ni = 0; ni < 4; ++ni) {
      int off = (colH * 64 + ni * 16 + fr) * SC + kb;
      bf16x8 bh = ldsb8(sBh + off);
      bf16x8 bl = ldsb8(sBl + off);
      gacc[ni] = __builtin_amdgcn_mfma_f32_16x16x32_bf16(ah, bh, gacc[ni], 0, 0, 0);
      gacc[ni] = __builtin_amdgcn_mfma_f32_16x16x32_bf16(ah, bl, gacc[ni], 0, 0, 0);
      gacc[ni] = __builtin_amdgcn_mfma_f32_16x16x32_bf16(al, bh, gacc[ni], 0, 0, 0);
    }
  }
  __syncthreads();  // B2 (w table complete)

  // mask + split-store G
#pragma unroll
  for (int ni = 0; ni < 4; ++ni) {
    int colg = colH * 64 + ni * 16 + fr;
    int s = colg >> 1;
#pragma unroll
    for (int r = 0; r < 4; ++r) {
      int rowg = rowA0 + kq * 4 + r;
      int t = rowg >> 1;
      float gm = gacc[ni][r] * sW[t * SW + s];
      unsigned short hh, ll;
      split2(gm, hh, ll);
      sGh[rowg * SG + colg] = hh;
      sGl[rowg * SG + colg] = ll;
    }
  }
  __syncthreads();  // B3 (w fully consumed)

  // stage h0^T (into w region)
  for (int m = tid; m < 4096; m += 1024) {
    int n = m >> 6, p = m & 63;
    float v = hstate[(size_t)bid * 4096 + m];
    unsigned short hh, ll;
    split2(v, hh, ll);
    sHh[p * SH + n] = hh;
    sHl[p * SH + n] = ll;
  }
  __syncthreads();  // B4

  // y0 = (C · h0^T) * elx[t] ; wave rows rowA0, p half colH*32
  f32x4 yac[2];
#pragma unroll
  for (int j = 0; j < 2; ++j) yac[j] = (f32x4){0.f, 0.f, 0.f, 0.f};
#pragma unroll
  for (int ks = 0; ks < 2; ++ks) {
    int kb = ks * 32 + kq * 8;
    int offA = (rowA0 + fr) * SC + kb;
    bf16x8 ah = ldsb8(sCh + offA);
    bf16x8 al = ldsb8(sCl + offA);
#pragma unroll
    for (int ni = 0; ni < 2; ++ni) {
      int off = (colH * 32 + ni * 16 + fr) * SH + kb;
      bf16x8 bh = ldsb8(sHh + off);
      bf16x8 bl = ldsb8(sHl + off);
      yac[ni] = __builtin_amdgcn_mfma_f32_16x16x32_bf16(ah, bh, yac[ni], 0, 0, 0);
      yac[ni] = __builtin_amdgcn_mfma_f32_16x16x32_bf16(ah, bl, yac[ni], 0, 0, 0);
      yac[ni] = __builtin_amdgcn_mfma_f32_16x16x32_bf16(al, bh, yac[ni], 0, 0, 0);
    }
  }
#pragma unroll
  for (int r = 0; r < 4; ++r) {
    int t = (rowA0 + kq * 4 + r) >> 1;
    float e = selx[t];
#pragma unroll
    for (int ni = 0; ni < 2; ++ni) yac[ni][r] *= e;
  }
  __syncthreads();  // B5 (sC consumed)

  // stage X^T (over sC region) and Wd (over sB region)
  for (int m = tid; m < 8192; m += 1024) {
    int s = m >> 7, j = m & 127;
    float xv = xmoe[((tok0 + s) * kH + h) * (size_t)128 + j];
    int p = j >> 1, cc = s * 2 + (j & 1);
    unsigned short hh, ll;
    split2(xv, hh, ll);
    sXh[p * SG + cc] = hh; sXl[p * SG + cc] = ll;
    float wv = ydown[m];
    split2(wv, hh, ll);
    sWdh[(m >> 7) * SG + (m & 127)] = hh;
    sWdl[(m >> 7) * SG + (m & 127)] = ll;
  }
  __syncthreads();  // B6

  // yac += G · X^T   (K = 128)
#pragma unroll
  for (int ks = 0; ks < 4; ++ks) {
    int kb = ks * 32 + kq * 8;
    int offA = (rowA0 + fr) * SG + kb;
    bf16x8 ah = ldsb8(sGh + offA);
    bf16x8 al = ldsb8(sGl + offA);
#pragma unroll
    for (int ni = 0; ni < 2; ++ni) {
      int off = (colH * 32 + ni * 16 + fr) * SG + kb;
      bf16x8 bh = ldsb8(sXh + off);
      bf16x8 bl = ldsb8(sXl + off);
      yac[ni] = __builtin_amdgcn_mfma_f32_16x16x32_bf16(ah, bh, yac[ni], 0, 0, 0);
      yac[ni] = __builtin_amdgcn_mfma_f32_16x16x32_bf16(ah, bl, yac[ni], 0, 0, 0);
      yac[ni] = __builtin_amdgcn_mfma_f32_16x16x32_bf16(al, bh, yac[ni], 0, 0, 0);
    }
  }
  __syncthreads();  // B7 (sG consumed)

  // write Ys[t][p*2+r] (into sG region)
#pragma unroll
  for (int ni = 0; ni < 2; ++ni)
#pragma unroll
    for (int r = 0; r < 4; ++r) {
      int rowg = rowA0 + kq * 4 + r;
      int t = rowg >> 1, rr = rowg & 1;
      int p = colH * 32 + ni * 16 + fr;
      unsigned short hh, ll;
      split2(yac[ni][r], hh, ll);
      sYh[t * SG + p * 2 + rr] = hh;
      sYl[t * SG + p * 2 + rr] = ll;
    }
  __syncthreads();  // B8

  // Z = Ys · Wd^T (64x64, K=128); wave grid: rows (wave&3)*16, cols (wave>>2)*16
  f32x4 zac = (f32x4){0.f, 0.f, 0.f, 0.f};
  const int zr0 = (wave & 3) * 16, zc0 = (wave >> 2) * 16;
#pragma unroll
  for (int ks = 0; ks < 4; ++ks) {
    int kb = ks * 32 + kq * 8;
    int offA = (zr0 + fr) * SG + kb;
    bf16x8 ah = ldsb8(sYh + offA);
    bf16x8 al = ldsb8(sYl + offA);
    int offB = (zc0 + fr) * SG + kb;
    bf16x8 bh = ldsb8(sWdh + offB);
    bf16x8 bl = ldsb8(sWdl + offB);
    zac = __builtin_amdgcn_mfma_f32_16x16x32_bf16(ah, bh, zac, 0, 0, 0);
    zac = __builtin_amdgcn_mfma_f32_16x16x32_bf16(ah, bl, zac, 0, 0, 0);
    zac = __builtin_amdgcn_mfma_f32_16x16x32_bf16(al, bh, zac, 0, 0, 0);
  }
#pragma unroll
  for (int r = 0; r < 4; ++r) {
    int t = zr0 + kq * 4 + r;
    int o = zc0 + fr;
    outY[(tok0 + t) * (size_t)1024 + h * 64 + o] = zac[r];
  }
}

// ---------------- K8: gate
__global__ __launch_bounds__(256) void k_gate(float* __restrict__ y,
                                              const float* __restrict__ proj,
                                              const float* __restrict__ Dv,
                                              const float* __restrict__ pregate_w) {
  int tok = blockIdx.x;
  int tid = threadIdx.x;
  size_t yoff = (size_t)tok * 1024;
  size_t poff = (size_t)tok * kDPROJ;
  __shared__ float red[4];
  float vals[4];
  float ss = 0.f;
#pragma unroll
  for (int q = 0; q < 4; ++q) {
    int j = tid + q * 256;
    float v = y[yoff + j] + proj[poff + COL_XP + j] * Dv[j >> 6];
    vals[q] = v;
    ss += v * v;
  }
  for (int o = 1; o < 64; o <<= 1) ss += __shfl_xor(ss, o);
  if ((tid & 63) == 0) red[tid >> 6] = ss;
  __syncthreads();
  float tot = red[0] + red[1] + red[2] + red[3];
  float scale = rsqrtf(tot / 1024.f + 1e-5f);
#pragma unroll
  for (int q = 0; q < 4; ++q) {
    int j = tid + q * 256;
    float z = proj[poff + COL_Z + j];
    float sig = 1.f / (1.f + expf(-z));
    y[yoff + j] = vals[q] * scale * pregate_w[j] * sig;
  }
}

// ---------------- K8b: oup router logits — coalesced, LDS-tiled, f64 accum
__global__ __launch_bounds__(256) void k_logits(const float* __restrict__ y,
                                                const float* __restrict__ router,
                                                float* __restrict__ logits) {
  __shared__ float Yt[16][65];
  __shared__ float Rt[64][65];
  int tid = threadIdx.x;
  int tok0 = blockIdx.x * 16;
  int t = tid & 15;
  int e0 = (tid >> 4) * 4;
  double acc[4] = {0.0, 0.0, 0.0, 0.0};
  for (int kc = 0; kc < 1024; kc += 64) {
    for (int m = tid; m < 1024; m += 256) {
      int tt = m >> 6, c = m & 63;
      Yt[tt][c] = y[(size_t)(tok0 + tt) * 1024 + kc + c];
    }
    for (int m = tid; m < 4096; m += 256) {
      int ee = m >> 6, c = m & 63;
      Rt[ee][c] = router[(size_t)ee * 1024 + kc + c];
    }
    __syncthreads();
    for (int c = 0; c < 64; ++c) {
      float yv = Yt[t][c];
#pragma unroll
      for (int i = 0; i < 4; ++i)
        acc[i] += (double)Rt[e0 + i][c] * (double)yv;
    }
    __syncthreads();
  }
#pragma unroll
  for (int i = 0; i < 4; ++i)
    logits[(size_t)(tok0 + t) * 64 + e0 + i] = (float)acc[i];
}

// ---------------- K9: oup Kron-MoE, in place on d_out (logits precomputed)
__global__ __launch_bounds__(256) void k_oup(float* __restrict__ y,
                                             const float* __restrict__ logits,
                                             const float* __restrict__ Ae,
                                             const float* __restrict__ Be,
                                             const float* __restrict__ scale_,
                                             const float* __restrict__ bias_) {
  int tok = blockIdx.x;
  int tid = threadIdx.x;
  __shared__ float xs[1024];
  __shared__ float Ts[32][33];
  __shared__ float lg[64];
  size_t yoff = (size_t)tok * 1024;
  for (int m = tid; m < 1024; m += 256) xs[m] = y[yoff + m];
  if (tid < 64) lg[tid] = logits[(size_t)tok * 64 + tid];
  __syncthreads();
  float v1 = -INFINITY; int i1 = -1;
  for (int e = 0; e < 64; ++e) { float v = lg[e]; if (v > v1) { v1 = v; i1 = e; } }
  float v2 = -INFINITY; int i2 = -1;
  for (int e = 0; e < 64; ++e) { if (e == i1) continue; float v = lg[e]; if (v > v2) { v2 = v; i2 = e; } }
  float e12 = expf(v2 - v1);
  float p1 = 1.f / (1.f + e12), p2 = e12 / (1.f + e12);
  float out[4] = {0.f, 0.f, 0.f, 0.f};
  for (int kk = 0; kk < 2; ++kk) {
    int e = kk ? i2 : i1;
    float pw = kk ? p2 : p1;
    const float* A = Ae + (size_t)e * 1024;
    const float* Bm = Be + (size_t)e * 1024;
    __syncthreads();
    for (int m = tid; m < 1024; m += 256) {
      int i = m >> 5, p = m & 31;
      float t = 0.f;
#pragma unroll
      for (int j = 0; j < 32; ++j) t += xs[i * 32 + j] * Bm[p * 32 + j];
      Ts[i][p] = t;
    }
    __syncthreads();
#pragma unroll
    for (int q = 0; q < 4; ++q) {
      int cc = tid + q * 256;
      int o = cc >> 5, p = cc & 31;
      float a2 = 0.f;
#pragma unroll
      for (int i = 0; i < 32; ++i) a2 += A[o * 32 + i] * Ts[i][p];
      out[q] += pw * a2;
    }
  }
  float sc = scale_[0];
#pragma unroll
  for (int q = 0; q < 4; ++q) {
    int cc = tid + q * 256;
    y[yoff + cc] = out[q] * sc + bias_[cc];
  }
}

extern "C" void kernel_launch(void* const* d_in, const int* in_sizes, int n_in,
                              void* d_out, int out_size, void* d_ws, size_t ws_size,
                              hipStream_t stream) {
  const float* u          = (const float*)d_in[0];
  const float* in_proj_w  = (const float*)d_in[1];
  const float* in_proj_b  = (const float*)d_in[2];
  const float* xup_router = (const float*)d_in[3];
  const float* xup_A      = (const float*)d_in[4];
  const float* xup_B      = (const float*)d_in[5];
  const float* xup_scale  = (const float*)d_in[6];
  const float* xup_bias   = (const float*)d_in[7];
  const float* ydown_w    = (const float*)d_in[8];
  const float* oup_router = (const float*)d_in[9];
  const float* oup_A      = (const float*)d_in[10];
  const float* oup_B      = (const float*)d_in[11];
  const float* oup_scale  = (const float*)d_in[12];
  const float* oup_bias   = (const float*)d_in[13];
  const float* theta_log  = (const float*)d_in[14];
  const float* Dv         = (const float*)d_in[15];
  const float* normB_w    = (const float*)d_in[16];
  const float* normC_w    = (const float*)d_in[17];
  const float* bias_B     = (const float*)d_in[18];
  const float* bias_C     = (const float*)d_in[19];
  const float* pregate_w  = (const float*)d_in[20];

  char* ws = (char*)d_ws;
  float* proj = (float*)ws;      ws += (size_t)kTOK * kDPROJ * 4;
  float* dtg = (float*)ws;       ws += (size_t)kTOK * kG * 4;
  float* cumalog = (float*)ws;   ws += (size_t)kTOK * kG * 4;
  double* cumdt = (double*)ws;   ws += (size_t)kTOK * kG * 8;
  float* cs_tab = (float*)ws;    ws += (size_t)kTOK * kG * 32 * 2 * 4;
  float* xmoe = (float*)ws;      ws += (size_t)kTOK * kH * 128 * 4;
  float* hstate = (float*)ws;    ws += (size_t)kB * kH * kNC * 4096 * 4;
  float* outY = (float*)d_out;

  float* logits = cs_tab;  // aliases cs_tab (dead after k_rotate)

  unsigned short* Uhi = (unsigned short*)xmoe;
  unsigned short* Ulo = Uhi + (size_t)kTOK * kDM;
  unsigned short* Whi = Ulo + (size_t)kTOK * kDM;
  unsigned short* Wlo = Whi + (size_t)kNPAD * kDM;

  k_split_u<<<dim3(kTOK * kDM / 4 / 256), dim3(256), 0, stream>>>(u, Uhi, Ulo);
  k_split_w<<<dim3(kNPAD * kDM / 4 / 256), dim3(256), 0, stream>>>(in_proj_w, Whi, Wlo);
  k_inproj_mfma<<<dim3(kTOK / 128, kNPAD / 128), dim3(256), 0, stream>>>(Uhi, Ulo, Whi, Wlo, in_proj_b, proj);
  k_dtprep<<<dim3(kB * kG), dim3(256), 0, stream>>>(proj, dtg, cumalog, cumdt);
  k_angles<<<dim3(kTOK * 128 / 256), dim3(256), 0, stream>>>(cumdt, theta_log, cs_tab);
  k_rotate<<<dim3(kTOK), dim3(256), 0, stream>>>(proj, cs_tab, normB_w, normC_w, bias_B, bias_C);
  k_xup<<<dim3(kTOK * kH / 4), dim3(256), 0, stream>>>(proj, xup_router, xup_A, xup_B, xup_scale, xup_bias, xmoe);
  k_passA<<<dim3(kB * kH * kNC), dim3(256), 0, stream>>>(proj, xmoe, dtg, cumalog, hstate);
  k_passB<<<dim3(kB * kH), dim3(256), 0, stream>>>(hstate, cumalog);
  k_passC<<<dim3(kB * kH * kNC), dim3(1024), 0, stream>>>(proj, xmoe, dtg, cumalog, hstate, ydown_w, outY);
  k_gate<<<dim3(kTOK), dim3(256), 0, stream>>>(outY, proj, Dv, pregate_w);
  k_logits<<<dim3(kTOK / 16), dim3(256), 0, stream>>>(outY, oup_router, logits);
  k_oup<<<dim3(kTOK), dim3(256), 0, stream>>>(outY, logits, oup_A, oup_B, oup_scale, oup_bias);
}